// Round 4
// baseline (391.882 us; speedup 1.0000x reference)
//
#include <hip/hip_runtime.h>
#include <stdint.h>

#define HGT   24
#define WID   24
#define NHEAD 12
#define EMB   768
#define HD    64
#define NGRID 576
#define NTOK  577
#define NPAD  640              // padded token dim (10 tiles of 64)
#define BATCH 32
#define MROWS (BATCH * NTOK)   // 18464
#define NQT   10
#define NKT   10
#define QKVC  (3 * EMB)        // 2304

typedef __attribute__((ext_vector_type(8))) short bf16x8;
typedef __attribute__((ext_vector_type(4))) float f32x4;

__device__ __forceinline__ short f2bf(float f) {
    union { float f; unsigned u; } c; c.f = f;
    unsigned r = (c.u + 0x7FFFu + ((c.u >> 16) & 1u)) >> 16;
    return (short)(r & 0xFFFFu);
}

// async global->LDS, 16B per lane; LDS dest = wave-uniform base + lane*16
__device__ __forceinline__ void gload16(void* lds, const void* g) {
    __builtin_amdgcn_global_load_lds(
        (const __attribute__((address_space(1))) void*)g,
        (__attribute__((address_space(3))) void*)lds, 16, 0, 0);
}

__device__ __forceinline__ void wait_vm0_barrier() {
    asm volatile("s_waitcnt vmcnt(0)" ::: "memory");
    __builtin_amdgcn_s_barrier();
}

// ---------------------------------------------------------------- cast f32->bf16
__global__ void cast_f32_bf16(const float* __restrict__ src, short* __restrict__ dst, int n) {
    int i = (blockIdx.x * blockDim.x + threadIdx.x) * 4;
    int stride = gridDim.x * blockDim.x * 4;
    for (int j = i; j < n; j += stride) {
        float4 v = *(const float4*)(src + j);
        short4 o;
        o.x = f2bf(v.x); o.y = f2bf(v.y); o.z = f2bf(v.z); o.w = f2bf(v.w);
        *(short4*)(dst + j) = o;
    }
}

// ---------------------------------------------------------------- padded bias table [H][640][640]
__global__ void bias_expand(const float* __restrict__ rel, float* __restrict__ be) {
    int q = blockIdx.x;     // 0..639
    int k = threadIdx.x;    // 0..639
    float v[NHEAD];
    if (k >= NTOK) {
#pragma unroll
        for (int h = 0; h < NHEAD; h++) v[h] = -1e30f;
    } else if (q == 0 || q >= NTOK || k == 0) {
#pragma unroll
        for (int h = 0; h < NHEAD; h++) v[h] = 0.f;
    } else {
        int i = q - 1, j = k - 1;
        int idx = ((i / WID) - (j / WID) + HGT - 1) * (2 * WID - 1)
                + ((i % WID) - (j % WID) + WID - 1);
        const float* rp = rel + (size_t)idx * NHEAD;
#pragma unroll
        for (int h = 0; h < NHEAD; h++) v[h] = rp[h];
    }
#pragma unroll
    for (int h = 0; h < NHEAD; h++)
        be[((size_t)h * NPAD + q) * NPAD + k] = v[h];
}

// ---------------------------------------------------------------- V transpose from qnat: vt[b][h][d][key(640)]
__global__ __launch_bounds__(256) void transpose_v(const short* __restrict__ qnat, short* __restrict__ vt) {
    __shared__ __align__(16) short T[64][72];
    int bi = blockIdx.x;
    int kt = bi % NKT;
    int h  = (bi / NKT) % NHEAD;
    int b  = bi / (NKT * NHEAD);
    int t  = threadIdx.x;

    int r  = t >> 2, cb = (t & 3) * 16;
    int key = kt * 64 + r; if (key >= NTOK) key = NTOK - 1;
    const short* src = qnat + (size_t)(b * NTOK + key) * QKVC + 2 * EMB + h * HD;
    *(int4*)&T[r][cb]     = *(const int4*)(src + cb);
    *(int4*)&T[r][cb + 8] = *(const int4*)(src + cb + 8);
    __syncthreads();

    int d = t >> 2, kb = (t & 3) * 16;
    short tmp[16];
#pragma unroll
    for (int s = 0; s < 16; s++) tmp[s] = T[kb + s][d];
    short* dst = vt + (((size_t)b * NHEAD + h) * HD + d) * NPAD + kt * 64 + kb;
    *(int4*)&dst[0] = *(int4*)&tmp[0];
    *(int4*)&dst[8] = *(int4*)&tmp[8];
}

// ---------------------------------------------------------------- GEMM  C = A @ B^T (+bias)
// A: [M][768] bf16 ; Bw: [NC][768] bf16
// MODE 0: NC=2304, bf16 out -> qnat[m][2304], biases b0|b1|b2 per 768-col third
// MODE 1: NC=768,  f32 out + b0
template <int MODE>
__global__ __launch_bounds__(256) void gemm_bt(
    const short* __restrict__ A, const short* __restrict__ Bw,
    const float* __restrict__ b0, const float* __restrict__ b1, const float* __restrict__ b2,
    void* __restrict__ Outp, int M)
{
    constexpr int NC = (MODE == 0) ? QKVC : EMB;
    constexpr int K  = EMB;
    constexpr int NST = K / 64;   // 12

    __shared__ __align__(16) short Asl[2][128][64];
    __shared__ __align__(16) short Bsl[2][128][64];

    const int t    = threadIdx.x;
    const int lane = t & 63;
    const int w    = t >> 6;
    const int wr   = (w >> 1) * 64;
    const int wc   = (w & 1) * 64;
    const int lg   = lane >> 4;
    const int li   = lane & 15;
    const int xh   = li & 7;
    const int tm   = blockIdx.y * 128;
    const int tn   = blockIdx.x * 128;

    // staging: lane l of wave w (issue p) -> LDS row p*32 + w*8 + (l>>3), phys chunk l&7
    // source pre-swizzled: logical chunk (l&7)^(row&7), row&7 = l>>3
    const int srow = w * 8 + (lane >> 3);
    const int cofs = ((lane & 7) ^ (lane >> 3)) * 8;

    const short* ag[4];
    const short* bg[4];
#pragma unroll
    for (int p = 0; p < 4; p++) {
        int rm = tm + p * 32 + srow; if (rm >= M) rm = M - 1;
        ag[p] = A  + (size_t)rm * K + cofs;
        bg[p] = Bw + (size_t)(tn + p * 32 + srow) * K + cofs;
    }

    f32x4 acc[4][4];
#pragma unroll
    for (int i = 0; i < 4; i++)
#pragma unroll
        for (int j = 0; j < 4; j++) acc[i][j] = (f32x4){0.f, 0.f, 0.f, 0.f};

    // prologue: stage step 0 into buf 0
#pragma unroll
    for (int p = 0; p < 4; p++) {
        gload16(&Asl[0][p * 32 + w * 8][0], ag[p]);
        gload16(&Bsl[0][p * 32 + w * 8][0], bg[p]);
    }
    wait_vm0_barrier();

    short (*Ac)[64] = Asl[0], (*An)[64] = Asl[1];
    short (*Bc)[64] = Bsl[0], (*Bn)[64] = Bsl[1];

    for (int step = 0; step < NST; step++) {
        // issue next-tile loads first (they complete under the MFMAs below)
        if (step + 1 < NST) {
            int k0 = (step + 1) * 64;
#pragma unroll
            for (int p = 0; p < 4; p++) {
                gload16(&An[p * 32 + w * 8][0], ag[p] + k0);
                gload16(&Bn[p * 32 + w * 8][0], bg[p] + k0);
            }
        }
        // compute current buffer
#pragma unroll
        for (int kk = 0; kk < 2; kk++) {
            bf16x8 af[4], bfr[4];
#pragma unroll
            for (int i = 0; i < 4; i++)
                af[i]  = *(const bf16x8*)&Ac[wr + i * 16 + li][((kk * 4 + lg) ^ xh) * 8];
#pragma unroll
            for (int j = 0; j < 4; j++)
                bfr[j] = *(const bf16x8*)&Bc[wc + j * 16 + li][((kk * 4 + lg) ^ xh) * 8];
#pragma unroll
            for (int i = 0; i < 4; i++)
#pragma unroll
                for (int j = 0; j < 4; j++)
                    acc[i][j] = __builtin_amdgcn_mfma_f32_16x16x32_bf16(af[i], bfr[j], acc[i][j], 0, 0, 0);
        }
        wait_vm0_barrier();     // next tile landed; all reads of current done
        short (*tp)[64];
        tp = Ac; Ac = An; An = tp;
        tp = Bc; Bc = Bn; Bn = tp;
    }

    // epilogue: natural layout, trivial addressing
#pragma unroll
    for (int j = 0; j < 4; j++) {
        int c = tn + wc + j * 16 + li;
        float bias;
        if constexpr (MODE == 0) {
            int which = (c >= 2 * EMB) ? 2 : ((c >= EMB) ? 1 : 0);
            const float* bb = (which == 0) ? b0 : ((which == 1) ? b1 : b2);
            bias = bb[c - which * EMB];
        } else {
            bias = b0[c];
        }
#pragma unroll
        for (int i = 0; i < 4; i++) {
#pragma unroll
            for (int r = 0; r < 4; r++) {
                int m = tm + wr + i * 16 + lg * 4 + r;
                if (m >= M) continue;
                float v = acc[i][j][r] + bias;
                if constexpr (MODE == 0)
                    ((short*)Outp)[(size_t)m * NC + c] = f2bf(v);
                else
                    ((float*)Outp)[(size_t)m * NC + c] = v;
            }
        }
    }
}

// ---------------------------------------------------------------- flash attention
__global__ __launch_bounds__(256) void attn_kernel(
    const short* __restrict__ qnat, const short* __restrict__ vt,
    const float* __restrict__ biasx, short* __restrict__ aout)
{
    __shared__ __align__(16) short Ksl[2][64][64];
    __shared__ __align__(16) short Vsl[2][64][64];   // [d][key_local]
    __shared__ __align__(16) short Psl[4][16][72];

    const int bi = blockIdx.x;
    const int qt = bi % NQT;
    const int h  = (bi / NQT) % NHEAD;
    const int b  = bi / (NQT * NHEAD);
    const int t    = threadIdx.x;
    const int lane = t & 63;
    const int w    = t >> 6;
    const int lg   = lane >> 4;
    const int li   = lane & 15;
    const int xh   = li & 7;
    const int qbase = qt * 64;

    const short* qp  = qnat + (size_t)b * NTOK * QKVC + h * HD;          // + n*QKVC
    const short* kp  = qp + EMB;
    const short* vtp = vt + ((size_t)b * NHEAD + h) * (size_t)HD * NPAD;
    const float* brow = biasx + ((size_t)h * NPAD + qbase + w * 16 + lg * 4) * NPAD + li;

    bf16x8 qf[2];
    {
        int qrow = qbase + w * 16 + li; if (qrow >= NTOK) qrow = NTOK - 1;
        qf[0] = *(const bf16x8*)(qp + (size_t)qrow * QKVC + lg * 8);
        qf[1] = *(const bf16x8*)(qp + (size_t)qrow * QKVC + 32 + lg * 8);
    }

    float mrun[4], lrun[4];
    f32x4 oacc[4];
#pragma unroll
    for (int r = 0; r < 4; r++) { mrun[r] = -1e30f; lrun[r] = 0.f; }
#pragma unroll
    for (int d = 0; d < 4; d++) oacc[d] = (f32x4){0.f, 0.f, 0.f, 0.f};

    const int srow = w * 8 + (lane >> 3);
    const int cofs = ((lane & 7) ^ (lane >> 3)) * 8;

    // prologue: stage tile 0 into buf 0
#pragma unroll
    for (int p = 0; p < 2; p++) {
        int key = p * 32 + srow; if (key >= NTOK) key = NTOK - 1;
        gload16(&Ksl[0][p * 32 + w * 8][0], kp + (size_t)key * QKVC + cofs);
        gload16(&Vsl[0][p * 32 + w * 8][0], vtp + (size_t)(p * 32 + srow) * NPAD + cofs);
    }
    wait_vm0_barrier();

    short (*Kc)[64] = Ksl[0], (*Kn)[64] = Ksl[1];
    short (*Vc)[64] = Vsl[0], (*Vn)[64] = Vsl[1];

    for (int kt = 0; kt < NKT; kt++) {
        // issue next KV tile
        if (kt + 1 < NKT) {
#pragma unroll
            for (int p = 0; p < 2; p++) {
                int key = (kt + 1) * 64 + p * 32 + srow; if (key >= NTOK) key = NTOK - 1;
                gload16(&Kn[p * 32 + w * 8][0], kp + (size_t)key * QKVC + cofs);
                gload16(&Vn[p * 32 + w * 8][0], vtp + (size_t)(p * 32 + srow) * NPAD + (kt + 1) * 64 + cofs);
            }
        }

        // S = Q K^T + bias (branch-free; masking baked into padded table)
        const float* bp2 = brow + kt * 64;
        float pvv[4][4];
        __builtin_amdgcn_s_setprio(1);
#pragma unroll
        for (int j = 0; j < 4; j++) {
            bf16x8 bk0 = *(const bf16x8*)&Kc[j * 16 + li][(lg ^ xh) * 8];
            bf16x8 bk1 = *(const bf16x8*)&Kc[j * 16 + li][((4 + lg) ^ xh) * 8];
            f32x4 s = (f32x4){0.f, 0.f, 0.f, 0.f};
            s = __builtin_amdgcn_mfma_f32_16x16x32_bf16(qf[0], bk0, s, 0, 0, 0);
            s = __builtin_amdgcn_mfma_f32_16x16x32_bf16(qf[1], bk1, s, 0, 0, 0);
#pragma unroll
            for (int r = 0; r < 4; r++)
                pvv[j][r] = fmaf(s[r], 0.125f, bp2[r * NPAD + j * 16]);
        }
        __builtin_amdgcn_s_setprio(0);

        // online softmax per row
#pragma unroll
        for (int r = 0; r < 4; r++) {
            float mt = fmaxf(fmaxf(pvv[0][r], pvv[1][r]), fmaxf(pvv[2][r], pvv[3][r]));
#pragma unroll
            for (int mk = 1; mk < 16; mk <<= 1) mt = fmaxf(mt, __shfl_xor(mt, mk, 64));
            float nm  = fmaxf(mrun[r], mt);
            float fac = __expf(mrun[r] - nm);
            float rs  = 0.f;
#pragma unroll
            for (int j = 0; j < 4; j++) {
                float p = __expf(pvv[j][r] - nm);
                pvv[j][r] = p;
                rs += p;
            }
#pragma unroll
            for (int mk = 1; mk < 16; mk <<= 1) rs += __shfl_xor(rs, mk, 64);
            lrun[r] = lrun[r] * fac + rs;
            mrun[r] = nm;
#pragma unroll
            for (int d = 0; d < 4; d++) oacc[d][r] *= fac;
        }

        // P -> bf16 -> per-wave LDS (wave-private, no barrier)
#pragma unroll
        for (int j = 0; j < 4; j++)
#pragma unroll
            for (int r = 0; r < 4; r++)
                Psl[w][lg * 4 + r][j * 16 + li] = f2bf(pvv[j][r]);

        // O += P @ V
        __builtin_amdgcn_s_setprio(1);
#pragma unroll
        for (int dd = 0; dd < 4; dd++) {
#pragma unroll
            for (int kk = 0; kk < 2; kk++) {
                bf16x8 pa = *(const bf16x8*)&Psl[w][li][kk * 32 + lg * 8];
                bf16x8 bv = *(const bf16x8*)&Vc[dd * 16 + li][((kk * 4 + lg) ^ xh) * 8];
                oacc[dd] = __builtin_amdgcn_mfma_f32_16x16x32_bf16(pa, bv, oacc[dd], 0, 0, 0);
            }
        }
        __builtin_amdgcn_s_setprio(0);

        wait_vm0_barrier();
        short (*tp)[64];
        tp = Kc; Kc = Kn; Kn = tp;
        tp = Vc; Vc = Vn; Vn = tp;
    }

#pragma unroll
    for (int dd = 0; dd < 4; dd++) {
#pragma unroll
        for (int r = 0; r < 4; r++) {
            int q = qbase + w * 16 + lg * 4 + r;
            if (q >= NTOK) continue;
            float v = oacc[dd][r] / lrun[r];
            aout[((size_t)b * NTOK + q) * EMB + h * HD + dd * 16 + li] = f2bf(v);
        }
    }
}

// ---------------------------------------------------------------- launch
extern "C" void kernel_launch(void* const* d_in, const int* in_sizes, int n_in,
                              void* d_out, int out_size, void* d_ws, size_t ws_size,
                              hipStream_t stream) {
    (void)in_sizes; (void)n_in; (void)out_size; (void)ws_size;
    const float* x   = (const float*)d_in[0];
    const float* Wq  = (const float*)d_in[1];
    const float* bq  = (const float*)d_in[2];
    const float* Wk  = (const float*)d_in[3];
    const float* bk  = (const float*)d_in[4];
    const float* Wv  = (const float*)d_in[5];
    const float* bv  = (const float*)d_in[6];
    const float* Wp  = (const float*)d_in[7];
    const float* bp  = (const float*)d_in[8];
    const float* rel = (const float*)d_in[9];

    const size_t WN = (size_t)EMB * EMB;                    // 589824
    short* Wb   = (short*)d_ws;                             // [2304][768] bf16
    short* Wpb  = Wb + 3 * WN;                              // [768][768] bf16
    short* qnat = Wpb + WN;                                 // [MROWS][2304] bf16
    short* xb   = qnat + (size_t)MROWS * QKVC;              // [MROWS][768] bf16
    short* aout = xb;                                       // ALIAS: xb dead after gemm0
    short* vtb  = xb + (size_t)MROWS * EMB;                 // [B][H][HD][640] bf16
    float* bexp = (float*)(vtb + (size_t)BATCH * NHEAD * HD * NPAD); // [H][640][640] f32

    const int XN = MROWS * EMB;  // 14180352
    cast_f32_bf16<<<576, 256, 0, stream>>>(Wq, Wb, (int)WN);
    cast_f32_bf16<<<576, 256, 0, stream>>>(Wk, Wb + WN, (int)WN);
    cast_f32_bf16<<<576, 256, 0, stream>>>(Wv, Wb + 2 * WN, (int)WN);
    cast_f32_bf16<<<576, 256, 0, stream>>>(Wp, Wpb, (int)WN);
    cast_f32_bf16<<<13848, 256, 0, stream>>>(x, xb, XN);
    bias_expand<<<NPAD, NPAD, 0, stream>>>(rel, bexp);

    gemm_bt<0><<<dim3(18, 145), 256, 0, stream>>>(xb, Wb, bq, bk, bv, qnat, MROWS);
    transpose_v<<<BATCH * NHEAD * NKT, 256, 0, stream>>>(qnat, vtb);
    attn_kernel<<<BATCH * NHEAD * NQT, 256, 0, stream>>>(qnat, vtb, bexp, aout);
    gemm_bt<1><<<dim3(6, 145), 256, 0, stream>>>(aout, Wpb, bp, bp, bp, d_out, MROWS);
}

// Round 5
// 383.907 us; speedup vs baseline: 1.0208x; 1.0208x over previous
//
#include <hip/hip_runtime.h>
#include <stdint.h>

#define HGT   24
#define WID   24
#define NHEAD 12
#define EMB   768
#define HD    64
#define NGRID 576
#define NTOK  577
#define NPAD  640              // padded token dim (10 tiles of 64)
#define BATCH 32
#define MROWS (BATCH * NTOK)   // 18464
#define NKT   10
#define NQT   5                // 5 q-tiles of 128
#define QKVC  (3 * EMB)        // 2304

typedef __attribute__((ext_vector_type(8))) short bf16x8;
typedef __attribute__((ext_vector_type(4))) float f32x4;

__device__ __forceinline__ short f2bf(float f) {
    union { float f; unsigned u; } c; c.f = f;
    unsigned r = (c.u + 0x7FFFu + ((c.u >> 16) & 1u)) >> 16;
    return (short)(r & 0xFFFFu);
}
__device__ __forceinline__ float b2f(short s) {
    union { unsigned u; float f; } c; c.u = ((unsigned)(unsigned short)s) << 16;
    return c.f;
}

// async global->LDS, 16B per lane; LDS dest = wave-uniform base + lane*16
__device__ __forceinline__ void gload16(void* lds, const void* g) {
    __builtin_amdgcn_global_load_lds(
        (const __attribute__((address_space(1))) void*)g,
        (__attribute__((address_space(3))) void*)lds, 16, 0, 0);
}

__device__ __forceinline__ void wait_vm0_barrier() {
    asm volatile("s_waitcnt vmcnt(0)" ::: "memory");
    __builtin_amdgcn_s_barrier();
}

// ---------------------------------------------------------------- cast f32->bf16
__global__ void cast_f32_bf16(const float* __restrict__ src, short* __restrict__ dst, int n) {
    int i = (blockIdx.x * blockDim.x + threadIdx.x) * 4;
    int stride = gridDim.x * blockDim.x * 4;
    for (int j = i; j < n; j += stride) {
        float4 v = *(const float4*)(src + j);
        short4 o;
        o.x = f2bf(v.x); o.y = f2bf(v.y); o.z = f2bf(v.z); o.w = f2bf(v.w);
        *(short4*)(dst + j) = o;
    }
}

// ---------------------------------------------------------------- bias table TRANSPOSED bf16 [H][k 640][q 640]
// block = k, thread = q (coalesced writes). k>=577 -> -1e30 (pad-key mask);
// q==0 / q>=577 / k==0 (CLS) -> 0.
__global__ void bias_expand(const float* __restrict__ rel, short* __restrict__ be) {
    int k = blockIdx.x;     // key   0..639
    int q = threadIdx.x;    // query 0..639
    float v[NHEAD];
    if (k >= NTOK) {
#pragma unroll
        for (int h = 0; h < NHEAD; h++) v[h] = -1e30f;
    } else if (q == 0 || q >= NTOK || k == 0) {
#pragma unroll
        for (int h = 0; h < NHEAD; h++) v[h] = 0.f;
    } else {
        int i = q - 1, j = k - 1;
        int idx = ((i / WID) - (j / WID) + HGT - 1) * (2 * WID - 1)
                + ((i % WID) - (j % WID) + WID - 1);
        const float* rp = rel + (size_t)idx * NHEAD;
#pragma unroll
        for (int h = 0; h < NHEAD; h++) v[h] = rp[h];
    }
#pragma unroll
    for (int h = 0; h < NHEAD; h++)
        be[((size_t)h * NPAD + k) * NPAD + q] = f2bf(v[h]);
}

// ---------------------------------------------------------------- V transpose from qnat: vt[b][h][d][key(640)]
__global__ __launch_bounds__(256) void transpose_v(const short* __restrict__ qnat, short* __restrict__ vt) {
    __shared__ __align__(16) short T[64][72];
    int bi = blockIdx.x;
    int kt = bi % NKT;
    int h  = (bi / NKT) % NHEAD;
    int b  = bi / (NKT * NHEAD);
    int t  = threadIdx.x;

    int r  = t >> 2, cb = (t & 3) * 16;
    int key = kt * 64 + r; if (key >= NTOK) key = NTOK - 1;
    const short* src = qnat + (size_t)(b * NTOK + key) * QKVC + 2 * EMB + h * HD;
    *(int4*)&T[r][cb]     = *(const int4*)(src + cb);
    *(int4*)&T[r][cb + 8] = *(const int4*)(src + cb + 8);
    __syncthreads();

    int d = t >> 2, kb = (t & 3) * 16;
    short tmp[16];
#pragma unroll
    for (int s = 0; s < 16; s++) tmp[s] = T[kb + s][d];
    short* dst = vt + (((size_t)b * NHEAD + h) * HD + d) * NPAD + kt * 64 + kb;
    *(int4*)&dst[0] = *(int4*)&tmp[0];
    *(int4*)&dst[8] = *(int4*)&tmp[8];
}

// ---------------------------------------------------------------- GEMM  C = A @ B^T (+bias)
// MODE 0: NC=2304, bf16 out -> qnat[m][2304]; MODE 1: NC=768, f32 out + b0
template <int MODE>
__global__ __launch_bounds__(256) void gemm_bt(
    const short* __restrict__ A, const short* __restrict__ Bw,
    const float* __restrict__ b0, const float* __restrict__ b1, const float* __restrict__ b2,
    void* __restrict__ Outp, int M)
{
    constexpr int NC = (MODE == 0) ? QKVC : EMB;
    constexpr int K  = EMB;
    constexpr int NST = K / 64;   // 12

    __shared__ __align__(16) short Asl[2][128][64];
    __shared__ __align__(16) short Bsl[2][128][64];

    const int t    = threadIdx.x;
    const int lane = t & 63;
    const int w    = t >> 6;
    const int wr   = (w >> 1) * 64;
    const int wc   = (w & 1) * 64;
    const int lg   = lane >> 4;
    const int li   = lane & 15;
    const int xh   = li & 7;
    const int tm   = blockIdx.y * 128;
    const int tn   = blockIdx.x * 128;

    const int srow = w * 8 + (lane >> 3);
    const int cofs = ((lane & 7) ^ (lane >> 3)) * 8;

    const short* ag[4];
    const short* bg[4];
#pragma unroll
    for (int p = 0; p < 4; p++) {
        int rm = tm + p * 32 + srow; if (rm >= M) rm = M - 1;
        ag[p] = A  + (size_t)rm * K + cofs;
        bg[p] = Bw + (size_t)(tn + p * 32 + srow) * K + cofs;
    }

    f32x4 acc[4][4];
#pragma unroll
    for (int i = 0; i < 4; i++)
#pragma unroll
        for (int j = 0; j < 4; j++) acc[i][j] = (f32x4){0.f, 0.f, 0.f, 0.f};

#pragma unroll
    for (int p = 0; p < 4; p++) {
        gload16(&Asl[0][p * 32 + w * 8][0], ag[p]);
        gload16(&Bsl[0][p * 32 + w * 8][0], bg[p]);
    }
    wait_vm0_barrier();

    short (*Ac)[64] = Asl[0], (*An)[64] = Asl[1];
    short (*Bc)[64] = Bsl[0], (*Bn)[64] = Bsl[1];

    for (int step = 0; step < NST; step++) {
        if (step + 1 < NST) {
            int k0 = (step + 1) * 64;
#pragma unroll
            for (int p = 0; p < 4; p++) {
                gload16(&An[p * 32 + w * 8][0], ag[p] + k0);
                gload16(&Bn[p * 32 + w * 8][0], bg[p] + k0);
            }
        }
#pragma unroll
        for (int kk = 0; kk < 2; kk++) {
            bf16x8 af[4], bfr[4];
#pragma unroll
            for (int i = 0; i < 4; i++)
                af[i]  = *(const bf16x8*)&Ac[wr + i * 16 + li][((kk * 4 + lg) ^ xh) * 8];
#pragma unroll
            for (int j = 0; j < 4; j++)
                bfr[j] = *(const bf16x8*)&Bc[wc + j * 16 + li][((kk * 4 + lg) ^ xh) * 8];
#pragma unroll
            for (int i = 0; i < 4; i++)
#pragma unroll
                for (int j = 0; j < 4; j++)
                    acc[i][j] = __builtin_amdgcn_mfma_f32_16x16x32_bf16(af[i], bfr[j], acc[i][j], 0, 0, 0);
        }
        wait_vm0_barrier();
        short (*tp)[64];
        tp = Ac; Ac = An; An = tp;
        tp = Bc; Bc = Bn; Bn = tp;
    }

#pragma unroll
    for (int j = 0; j < 4; j++) {
        int c = tn + wc + j * 16 + li;
        float bias;
        if constexpr (MODE == 0) {
            int which = (c >= 2 * EMB) ? 2 : ((c >= EMB) ? 1 : 0);
            const float* bb = (which == 0) ? b0 : ((which == 1) ? b1 : b2);
            bias = bb[c - which * EMB];
        } else {
            bias = b0[c];
        }
#pragma unroll
        for (int i = 0; i < 4; i++) {
#pragma unroll
            for (int r = 0; r < 4; r++) {
                int m = tm + wr + i * 16 + lg * 4 + r;
                if (m >= M) continue;
                float v = acc[i][j][r] + bias;
                if constexpr (MODE == 0)
                    ((short*)Outp)[(size_t)m * NC + c] = f2bf(v);
                else
                    ((float*)Outp)[(size_t)m * NC + c] = v;
            }
        }
    }
}

// ---------------------------------------------------------------- flash attention
// 512 threads (8 waves x 16 q-rows = 128 q per block), 5 q-tiles per (b,h)
__global__ __launch_bounds__(512) void attn_kernel(
    const short* __restrict__ qnat, const short* __restrict__ vt,
    const short* __restrict__ biasx, short* __restrict__ aout)
{
    __shared__ __align__(16) short Ksl[2][64][64];
    __shared__ __align__(16) short Vsl[2][64][64];   // [d][key_local]
    __shared__ __align__(16) short Psl[8][16][72];

    const int bi = blockIdx.x;
    const int qt = bi % NQT;
    const int h  = (bi / NQT) % NHEAD;
    const int b  = bi / (NQT * NHEAD);
    const int t    = threadIdx.x;
    const int lane = t & 63;
    const int w    = t >> 6;          // 0..7
    const int lg   = lane >> 4;
    const int li   = lane & 15;
    const int xh   = li & 7;
    const int qbase = qt * 128;

    const short* qp  = qnat + (size_t)b * NTOK * QKVC + h * HD;          // + n*QKVC
    const short* kp  = qp + EMB;
    const short* vtp = vt + ((size_t)b * NHEAD + h) * (size_t)HD * NPAD;
    const short* browt = biasx + (size_t)h * NPAD * NPAD;                 // [k][q] bf16
    const int qb0 = qbase + w * 16 + lg * 4;

    bf16x8 qf[2];
    {
        int qrow = qbase + w * 16 + li; if (qrow >= NTOK) qrow = NTOK - 1;
        qf[0] = *(const bf16x8*)(qp + (size_t)qrow * QKVC + lg * 8);
        qf[1] = *(const bf16x8*)(qp + (size_t)qrow * QKVC + 32 + lg * 8);
    }

    float mrun[4], lrun[4];
    f32x4 oacc[4];
#pragma unroll
    for (int r = 0; r < 4; r++) { mrun[r] = -1e30f; lrun[r] = 0.f; }
#pragma unroll
    for (int d = 0; d < 4; d++) oacc[d] = (f32x4){0.f, 0.f, 0.f, 0.f};

    // staging: wave w covers rows w*8..w*8+7; lane l -> row w*8+(l>>3), phys chunk l&7
    const int srow = w * 8 + (lane >> 3);
    const int cofs = ((lane & 7) ^ (lane >> 3)) * 8;

    {
        int key = srow; if (key >= NTOK) key = NTOK - 1;
        gload16(&Ksl[0][w * 8][0], kp + (size_t)key * QKVC + cofs);
        gload16(&Vsl[0][w * 8][0], vtp + (size_t)srow * NPAD + cofs);
    }
    wait_vm0_barrier();

    short (*Kc)[64] = Ksl[0], (*Kn)[64] = Ksl[1];
    short (*Vc)[64] = Vsl[0], (*Vn)[64] = Vsl[1];

    for (int kt = 0; kt < NKT; kt++) {
        if (kt + 1 < NKT) {
            int key = (kt + 1) * 64 + srow; if (key >= NTOK) key = NTOK - 1;
            gload16(&Kn[w * 8][0], kp + (size_t)key * QKVC + cofs);
            gload16(&Vn[w * 8][0], vtp + (size_t)srow * NPAD + (kt + 1) * 64 + cofs);
        }

        // S = Q K^T + bias (bias: transposed bf16 table -> one short4 per j)
        float pvv[4][4];
        __builtin_amdgcn_s_setprio(1);
#pragma unroll
        for (int j = 0; j < 4; j++) {
            short4 bs = *(const short4*)&browt[(size_t)(kt * 64 + j * 16 + li) * NPAD + qb0];
            bf16x8 bk0 = *(const bf16x8*)&Kc[j * 16 + li][(lg ^ xh) * 8];
            bf16x8 bk1 = *(const bf16x8*)&Kc[j * 16 + li][((4 + lg) ^ xh) * 8];
            f32x4 s = (f32x4){0.f, 0.f, 0.f, 0.f};
            s = __builtin_amdgcn_mfma_f32_16x16x32_bf16(qf[0], bk0, s, 0, 0, 0);
            s = __builtin_amdgcn_mfma_f32_16x16x32_bf16(qf[1], bk1, s, 0, 0, 0);
            pvv[j][0] = fmaf(s[0], 0.125f, b2f(bs.x));
            pvv[j][1] = fmaf(s[1], 0.125f, b2f(bs.y));
            pvv[j][2] = fmaf(s[2], 0.125f, b2f(bs.z));
            pvv[j][3] = fmaf(s[3], 0.125f, b2f(bs.w));
        }
        __builtin_amdgcn_s_setprio(0);

        // online softmax per row
#pragma unroll
        for (int r = 0; r < 4; r++) {
            float mt = fmaxf(fmaxf(pvv[0][r], pvv[1][r]), fmaxf(pvv[2][r], pvv[3][r]));
#pragma unroll
            for (int mk = 1; mk < 16; mk <<= 1) mt = fmaxf(mt, __shfl_xor(mt, mk, 64));
            float nm  = fmaxf(mrun[r], mt);
            float fac = __expf(mrun[r] - nm);
            float rs  = 0.f;
#pragma unroll
            for (int j = 0; j < 4; j++) {
                float p = __expf(pvv[j][r] - nm);
                pvv[j][r] = p;
                rs += p;
            }
#pragma unroll
            for (int mk = 1; mk < 16; mk <<= 1) rs += __shfl_xor(rs, mk, 64);
            lrun[r] = lrun[r] * fac + rs;
            mrun[r] = nm;
#pragma unroll
            for (int d = 0; d < 4; d++) oacc[d][r] *= fac;
        }

        // P -> bf16 -> per-wave LDS (wave-private, no barrier)
#pragma unroll
        for (int j = 0; j < 4; j++)
#pragma unroll
            for (int r = 0; r < 4; r++)
                Psl[w][lg * 4 + r][j * 16 + li] = f2bf(pvv[j][r]);

        // O += P @ V
        __builtin_amdgcn_s_setprio(1);
#pragma unroll
        for (int dd = 0; dd < 4; dd++) {
#pragma unroll
            for (int kk = 0; kk < 2; kk++) {
                bf16x8 pa = *(const bf16x8*)&Psl[w][li][kk * 32 + lg * 8];
                bf16x8 bv = *(const bf16x8*)&Vc[dd * 16 + li][((kk * 4 + lg) ^ xh) * 8];
                oacc[dd] = __builtin_amdgcn_mfma_f32_16x16x32_bf16(pa, bv, oacc[dd], 0, 0, 0);
            }
        }
        __builtin_amdgcn_s_setprio(0);

        wait_vm0_barrier();
        short (*tp)[64];
        tp = Kc; Kc = Kn; Kn = tp;
        tp = Vc; Vc = Vn; Vn = tp;
    }

#pragma unroll
    for (int dd = 0; dd < 4; dd++) {
#pragma unroll
        for (int r = 0; r < 4; r++) {
            int q = qbase + w * 16 + lg * 4 + r;
            if (q >= NTOK) continue;
            float v = oacc[dd][r] / lrun[r];
            aout[((size_t)b * NTOK + q) * EMB + h * HD + dd * 16 + li] = f2bf(v);
        }
    }
}

// ---------------------------------------------------------------- launch
extern "C" void kernel_launch(void* const* d_in, const int* in_sizes, int n_in,
                              void* d_out, int out_size, void* d_ws, size_t ws_size,
                              hipStream_t stream) {
    (void)in_sizes; (void)n_in; (void)out_size; (void)ws_size;
    const float* x   = (const float*)d_in[0];
    const float* Wq  = (const float*)d_in[1];
    const float* bq  = (const float*)d_in[2];
    const float* Wk  = (const float*)d_in[3];
    const float* bk  = (const float*)d_in[4];
    const float* Wv  = (const float*)d_in[5];
    const float* bv  = (const float*)d_in[6];
    const float* Wp  = (const float*)d_in[7];
    const float* bp  = (const float*)d_in[8];
    const float* rel = (const float*)d_in[9];

    const size_t WN = (size_t)EMB * EMB;                    // 589824
    short* Wb   = (short*)d_ws;                             // [2304][768] bf16
    short* Wpb  = Wb + 3 * WN;                              // [768][768] bf16
    short* qnat = Wpb + WN;                                 // [MROWS][2304] bf16
    short* xb   = qnat + (size_t)MROWS * QKVC;              // [MROWS][768] bf16
    short* aout = xb;                                       // ALIAS: xb dead after gemm0
    short* vtb  = xb + (size_t)MROWS * EMB;                 // [B][H][HD][640] bf16
    short* bexp = vtb + (size_t)BATCH * NHEAD * HD * NPAD;  // [H][640][640] bf16 (k-major)

    const int XN = MROWS * EMB;  // 14180352
    cast_f32_bf16<<<576, 256, 0, stream>>>(Wq, Wb, (int)WN);
    cast_f32_bf16<<<576, 256, 0, stream>>>(Wk, Wb + WN, (int)WN);
    cast_f32_bf16<<<576, 256, 0, stream>>>(Wv, Wb + 2 * WN, (int)WN);
    cast_f32_bf16<<<576, 256, 0, stream>>>(Wp, Wpb, (int)WN);
    cast_f32_bf16<<<13848, 256, 0, stream>>>(x, xb, XN);
    bias_expand<<<NPAD, NPAD, 0, stream>>>(rel, bexp);

    gemm_bt<0><<<dim3(18, 145), 256, 0, stream>>>(xb, Wb, bq, bk, bv, qnat, MROWS);
    transpose_v<<<BATCH * NHEAD * NKT, 256, 0, stream>>>(qnat, vtb);
    attn_kernel<<<BATCH * NHEAD * NQT, 512, 0, stream>>>(qnat, vtb, bexp, aout);
    gemm_bt<1><<<dim3(6, 145), 256, 0, stream>>>(aout, Wpb, bp, bp, bp, d_out, MROWS);
}

// Round 6
// 350.257 us; speedup vs baseline: 1.1188x; 1.0961x over previous
//
#include <hip/hip_runtime.h>
#include <stdint.h>

#define HGT   24
#define WID   24
#define NHEAD 12
#define EMB   768
#define HD    64
#define NGRID 576
#define NTOK  577
#define NPAD  640              // padded token dim (10 tiles of 64)
#define BATCH 32
#define MROWS (BATCH * NTOK)   // 18464
#define NKT   10
#define NQT   5                // 5 q-tiles of 128
#define QKVC  (3 * EMB)        // 2304

typedef __attribute__((ext_vector_type(8))) short bf16x8;
typedef __attribute__((ext_vector_type(4))) float f32x4;

__device__ __forceinline__ short f2bf(float f) {
    union { float f; unsigned u; } c; c.f = f;
    unsigned r = (c.u + 0x7FFFu + ((c.u >> 16) & 1u)) >> 16;
    return (short)(r & 0xFFFFu);
}
__device__ __forceinline__ float b2f(short s) {
    union { unsigned u; float f; } c; c.u = ((unsigned)(unsigned short)s) << 16;
    return c.f;
}

// async global->LDS, 16B per lane; LDS dest = wave-uniform base + lane*16
__device__ __forceinline__ void gload16(void* lds, const void* g) {
    __builtin_amdgcn_global_load_lds(
        (const __attribute__((address_space(1))) void*)g,
        (__attribute__((address_space(3))) void*)lds, 16, 0, 0);
}

__device__ __forceinline__ void wait_vm0_barrier() {
    asm volatile("s_waitcnt vmcnt(0)" ::: "memory");
    __builtin_amdgcn_s_barrier();
}

// ---------------------------------------------------------------- cast f32->bf16
__global__ void cast_f32_bf16(const float* __restrict__ src, short* __restrict__ dst, int n) {
    int i = (blockIdx.x * blockDim.x + threadIdx.x) * 4;
    int stride = gridDim.x * blockDim.x * 4;
    for (int j = i; j < n; j += stride) {
        float4 v = *(const float4*)(src + j);
        short4 o;
        o.x = f2bf(v.x); o.y = f2bf(v.y); o.z = f2bf(v.z); o.w = f2bf(v.w);
        *(short4*)(dst + j) = o;
    }
}

// ---------------------------------------------------------------- bias table bf16 [H][q 640][k 640]
// block = q, thread = k (coalesced writes). k>=577 -> -1e30 (pad-key mask);
// q==0 / q>=577 / k==0 (CLS) -> 0.
__global__ void bias_expand(const float* __restrict__ rel, short* __restrict__ be) {
    int q = blockIdx.x;     // query 0..639
    int k = threadIdx.x;    // key   0..639
    float v[NHEAD];
    if (k >= NTOK) {
#pragma unroll
        for (int h = 0; h < NHEAD; h++) v[h] = -1e30f;
    } else if (q == 0 || q >= NTOK || k == 0) {
#pragma unroll
        for (int h = 0; h < NHEAD; h++) v[h] = 0.f;
    } else {
        int i = q - 1, j = k - 1;
        int idx = ((i / WID) - (j / WID) + HGT - 1) * (2 * WID - 1)
                + ((i % WID) - (j % WID) + WID - 1);
        const float* rp = rel + (size_t)idx * NHEAD;
#pragma unroll
        for (int h = 0; h < NHEAD; h++) v[h] = rp[h];
    }
#pragma unroll
    for (int h = 0; h < NHEAD; h++)
        be[((size_t)h * NPAD + q) * NPAD + k] = f2bf(v[h]);
}

// ---------------------------------------------------------------- V transpose from qnat: vt[b][h][d][key(640)]
__global__ __launch_bounds__(256) void transpose_v(const short* __restrict__ qnat, short* __restrict__ vt) {
    __shared__ __align__(16) short T[64][72];
    int bi = blockIdx.x;
    int kt = bi % NKT;
    int h  = (bi / NKT) % NHEAD;
    int b  = bi / (NKT * NHEAD);
    int t  = threadIdx.x;

    int r  = t >> 2, cb = (t & 3) * 16;
    int key = kt * 64 + r; if (key >= NTOK) key = NTOK - 1;
    const short* src = qnat + (size_t)(b * NTOK + key) * QKVC + 2 * EMB + h * HD;
    *(int4*)&T[r][cb]     = *(const int4*)(src + cb);
    *(int4*)&T[r][cb + 8] = *(const int4*)(src + cb + 8);
    __syncthreads();

    int d = t >> 2, kb = (t & 3) * 16;
    short tmp[16];
#pragma unroll
    for (int s = 0; s < 16; s++) tmp[s] = T[kb + s][d];
    short* dst = vt + (((size_t)b * NHEAD + h) * HD + d) * NPAD + kt * 64 + kb;
    *(int4*)&dst[0] = *(int4*)&tmp[0];
    *(int4*)&dst[8] = *(int4*)&tmp[8];
}

// ---------------------------------------------------------------- GEMM  C = A @ B^T (+bias)
// MODE 0: NC=2304, bf16 out -> qnat[m][2304]; MODE 1: NC=768, f32 out + b0
template <int MODE>
__global__ __launch_bounds__(256) void gemm_bt(
    const short* __restrict__ A, const short* __restrict__ Bw,
    const float* __restrict__ b0, const float* __restrict__ b1, const float* __restrict__ b2,
    void* __restrict__ Outp, int M)
{
    constexpr int NC = (MODE == 0) ? QKVC : EMB;
    constexpr int K  = EMB;
    constexpr int NST = K / 64;   // 12

    __shared__ __align__(16) short Asl[2][128][64];
    __shared__ __align__(16) short Bsl[2][128][64];

    const int t    = threadIdx.x;
    const int lane = t & 63;
    const int w    = t >> 6;
    const int wr   = (w >> 1) * 64;
    const int wc   = (w & 1) * 64;
    const int lg   = lane >> 4;
    const int li   = lane & 15;
    const int xh   = li & 7;
    const int tm   = blockIdx.y * 128;
    const int tn   = blockIdx.x * 128;

    const int srow = w * 8 + (lane >> 3);
    const int cofs = ((lane & 7) ^ (lane >> 3)) * 8;

    const short* ag[4];
    const short* bg[4];
#pragma unroll
    for (int p = 0; p < 4; p++) {
        int rm = tm + p * 32 + srow; if (rm >= M) rm = M - 1;
        ag[p] = A  + (size_t)rm * K + cofs;
        bg[p] = Bw + (size_t)(tn + p * 32 + srow) * K + cofs;
    }

    f32x4 acc[4][4];
#pragma unroll
    for (int i = 0; i < 4; i++)
#pragma unroll
        for (int j = 0; j < 4; j++) acc[i][j] = (f32x4){0.f, 0.f, 0.f, 0.f};

#pragma unroll
    for (int p = 0; p < 4; p++) {
        gload16(&Asl[0][p * 32 + w * 8][0], ag[p]);
        gload16(&Bsl[0][p * 32 + w * 8][0], bg[p]);
    }
    wait_vm0_barrier();

    short (*Ac)[64] = Asl[0], (*An)[64] = Asl[1];
    short (*Bc)[64] = Bsl[0], (*Bn)[64] = Bsl[1];

    for (int step = 0; step < NST; step++) {
        if (step + 1 < NST) {
            int k0 = (step + 1) * 64;
#pragma unroll
            for (int p = 0; p < 4; p++) {
                gload16(&An[p * 32 + w * 8][0], ag[p] + k0);
                gload16(&Bn[p * 32 + w * 8][0], bg[p] + k0);
            }
        }
#pragma unroll
        for (int kk = 0; kk < 2; kk++) {
            bf16x8 af[4], bfr[4];
#pragma unroll
            for (int i = 0; i < 4; i++)
                af[i]  = *(const bf16x8*)&Ac[wr + i * 16 + li][((kk * 4 + lg) ^ xh) * 8];
#pragma unroll
            for (int j = 0; j < 4; j++)
                bfr[j] = *(const bf16x8*)&Bc[wc + j * 16 + li][((kk * 4 + lg) ^ xh) * 8];
#pragma unroll
            for (int i = 0; i < 4; i++)
#pragma unroll
                for (int j = 0; j < 4; j++)
                    acc[i][j] = __builtin_amdgcn_mfma_f32_16x16x32_bf16(af[i], bfr[j], acc[i][j], 0, 0, 0);
        }
        wait_vm0_barrier();
        short (*tp)[64];
        tp = Ac; Ac = An; An = tp;
        tp = Bc; Bc = Bn; Bn = tp;
    }

#pragma unroll
    for (int j = 0; j < 4; j++) {
        int c = tn + wc + j * 16 + li;
        float bias;
        if constexpr (MODE == 0) {
            int which = (c >= 2 * EMB) ? 2 : ((c >= EMB) ? 1 : 0);
            const float* bb = (which == 0) ? b0 : ((which == 1) ? b1 : b2);
            bias = bb[c - which * EMB];
        } else {
            bias = b0[c];
        }
#pragma unroll
        for (int i = 0; i < 4; i++) {
#pragma unroll
            for (int r = 0; r < 4; r++) {
                int m = tm + wr + i * 16 + lg * 4 + r;
                if (m >= M) continue;
                float v = acc[i][j][r] + bias;
                if constexpr (MODE == 0)
                    ((short*)Outp)[(size_t)m * NC + c] = f2bf(v);
                else
                    ((float*)Outp)[(size_t)m * NC + c] = v;
            }
        }
    }
}

// ---------------------------------------------------------------- flash attention (swapped QK^T)
// 512 threads (8 waves x 16 queries = 128 q per block), 5 q-tiles per (b,h)
// S^T = K @ Q^T : lane (lg,li) holds S^T[key=j*16+lg*4+r][q=qbase+w*16+li]
// O^T = V^T @ P^T : oacc[dd][r] = O^T[d=dd*16+lg*4+r][q]
__global__ __launch_bounds__(512) void attn_kernel(
    const short* __restrict__ qnat, const short* __restrict__ vt,
    const short* __restrict__ biasx, short* __restrict__ aout)
{
    __shared__ __align__(16) short Ksl[2][64][64];
    __shared__ __align__(16) short Vsl[2][64][64];   // [d][key_local]
    __shared__ __align__(16) short Psl[8][16][72];   // [wave][q(li)][key]

    const int bi = blockIdx.x;
    const int qt = bi % NQT;
    const int h  = (bi / NQT) % NHEAD;
    const int b  = bi / (NQT * NHEAD);
    const int t    = threadIdx.x;
    const int lane = t & 63;
    const int w    = t >> 6;          // 0..7
    const int lg   = lane >> 4;
    const int li   = lane & 15;
    const int xh   = li & 7;
    const int qbase = qt * 128;
    const int myq  = qbase + w * 16 + li;   // this lane's query column

    const short* qp  = qnat + (size_t)b * NTOK * QKVC + h * HD;          // + n*QKVC
    const short* kp  = qp + EMB;
    const short* vtp = vt + ((size_t)b * NHEAD + h) * (size_t)HD * NPAD;
    const short* browq = biasx + ((size_t)h * NPAD + myq) * NPAD;        // [k] bf16

    bf16x8 qf[2];   // B-fragment: Q[myq][k]
    {
        int qrow = myq < NTOK ? myq : NTOK - 1;
        qf[0] = *(const bf16x8*)(qp + (size_t)qrow * QKVC + lg * 8);
        qf[1] = *(const bf16x8*)(qp + (size_t)qrow * QKVC + 32 + lg * 8);
    }

    float mrun = -1e30f, lrun = 0.f;
    f32x4 oacc[4];
#pragma unroll
    for (int d = 0; d < 4; d++) oacc[d] = (f32x4){0.f, 0.f, 0.f, 0.f};

    // staging: wave w covers rows w*8..w*8+7; lane l -> row w*8+(l>>3), phys chunk l&7
    const int srow = w * 8 + (lane >> 3);
    const int cofs = ((lane & 7) ^ (lane >> 3)) * 8;

    {
        int key = srow; if (key >= NTOK) key = NTOK - 1;
        gload16(&Ksl[0][w * 8][0], kp + (size_t)key * QKVC + cofs);
        gload16(&Vsl[0][w * 8][0], vtp + (size_t)srow * NPAD + cofs);
    }
    wait_vm0_barrier();

    short (*Kc)[64] = Ksl[0], (*Kn)[64] = Ksl[1];
    short (*Vc)[64] = Vsl[0], (*Vn)[64] = Vsl[1];

    for (int kt = 0; kt < NKT; kt++) {
        if (kt + 1 < NKT) {
            int key = (kt + 1) * 64 + srow; if (key >= NTOK) key = NTOK - 1;
            gload16(&Kn[w * 8][0], kp + (size_t)key * QKVC + cofs);
            gload16(&Vn[w * 8][0], vtp + (size_t)srow * NPAD + (kt + 1) * 64 + cofs);
        }

        // S^T = K @ Q^T + bias^T
        float pvv[4][4];
        __builtin_amdgcn_s_setprio(1);
#pragma unroll
        for (int j = 0; j < 4; j++) {
            short4 bs = *(const short4*)&browq[kt * 64 + j * 16 + lg * 4];
            bf16x8 ak0 = *(const bf16x8*)&Kc[j * 16 + li][(lg ^ xh) * 8];
            bf16x8 ak1 = *(const bf16x8*)&Kc[j * 16 + li][((4 + lg) ^ xh) * 8];
            f32x4 s = (f32x4){0.f, 0.f, 0.f, 0.f};
            s = __builtin_amdgcn_mfma_f32_16x16x32_bf16(ak0, qf[0], s, 0, 0, 0);
            s = __builtin_amdgcn_mfma_f32_16x16x32_bf16(ak1, qf[1], s, 0, 0, 0);
            pvv[j][0] = fmaf(s[0], 0.125f, b2f(bs.x));
            pvv[j][1] = fmaf(s[1], 0.125f, b2f(bs.y));
            pvv[j][2] = fmaf(s[2], 0.125f, b2f(bs.z));
            pvv[j][3] = fmaf(s[3], 0.125f, b2f(bs.w));
        }
        __builtin_amdgcn_s_setprio(0);

        // online softmax: one query per lane; row spans the 4 lg-lanes (xor 16/32)
        float mt = pvv[0][0];
#pragma unroll
        for (int j = 0; j < 4; j++)
#pragma unroll
            for (int r = 0; r < 4; r++) mt = fmaxf(mt, pvv[j][r]);
        mt = fmaxf(mt, __shfl_xor(mt, 16, 64));
        mt = fmaxf(mt, __shfl_xor(mt, 32, 64));
        float nm  = fmaxf(mrun, mt);
        float fac = __expf(mrun - nm);
        float rs  = 0.f;
#pragma unroll
        for (int j = 0; j < 4; j++)
#pragma unroll
            for (int r = 0; r < 4; r++) {
                float p = __expf(pvv[j][r] - nm);
                pvv[j][r] = p;
                rs += p;
            }
        rs += __shfl_xor(rs, 16, 64);
        rs += __shfl_xor(rs, 32, 64);
        lrun = lrun * fac + rs;
        mrun = nm;
#pragma unroll
        for (int d = 0; d < 4; d++) oacc[d] *= fac;

        // P^T -> Psl[w][q=li][key] (wave-private, vectorized short4)
#pragma unroll
        for (int j = 0; j < 4; j++) {
            short4 ps;
            ps.x = f2bf(pvv[j][0]); ps.y = f2bf(pvv[j][1]);
            ps.z = f2bf(pvv[j][2]); ps.w = f2bf(pvv[j][3]);
            *(short4*)&Psl[w][li][j * 16 + lg * 4] = ps;
        }

        // O^T += V^T @ P^T
        __builtin_amdgcn_s_setprio(1);
#pragma unroll
        for (int dd = 0; dd < 4; dd++) {
#pragma unroll
            for (int kk = 0; kk < 2; kk++) {
                bf16x8 av = *(const bf16x8*)&Vc[dd * 16 + li][((kk * 4 + lg) ^ xh) * 8];
                bf16x8 pb = *(const bf16x8*)&Psl[w][li][kk * 32 + lg * 8];
                oacc[dd] = __builtin_amdgcn_mfma_f32_16x16x32_bf16(av, pb, oacc[dd], 0, 0, 0);
            }
        }
        __builtin_amdgcn_s_setprio(0);

        wait_vm0_barrier();
        short (*tp)[64];
        tp = Kc; Kc = Kn; Kn = tp;
        tp = Vc; Vc = Vn; Vn = tp;
    }

    // epilogue: O[q][d] = O^T[d][q]/l ; vectorized short4 stores
    if (myq < NTOK) {
        float inv = 1.0f / lrun;
        short* op = aout + ((size_t)b * NTOK + myq) * EMB + h * HD;
#pragma unroll
        for (int dd = 0; dd < 4; dd++) {
            short4 o;
            o.x = f2bf(oacc[dd][0] * inv);
            o.y = f2bf(oacc[dd][1] * inv);
            o.z = f2bf(oacc[dd][2] * inv);
            o.w = f2bf(oacc[dd][3] * inv);
            *(short4*)&op[dd * 16 + lg * 4] = o;
        }
    }
}

// ---------------------------------------------------------------- launch
extern "C" void kernel_launch(void* const* d_in, const int* in_sizes, int n_in,
                              void* d_out, int out_size, void* d_ws, size_t ws_size,
                              hipStream_t stream) {
    (void)in_sizes; (void)n_in; (void)out_size; (void)ws_size;
    const float* x   = (const float*)d_in[0];
    const float* Wq  = (const float*)d_in[1];
    const float* bq  = (const float*)d_in[2];
    const float* Wk  = (const float*)d_in[3];
    const float* bk  = (const float*)d_in[4];
    const float* Wv  = (const float*)d_in[5];
    const float* bv  = (const float*)d_in[6];
    const float* Wp  = (const float*)d_in[7];
    const float* bp  = (const float*)d_in[8];
    const float* rel = (const float*)d_in[9];

    const size_t WN = (size_t)EMB * EMB;                    // 589824
    short* Wb   = (short*)d_ws;                             // [2304][768] bf16
    short* Wpb  = Wb + 3 * WN;                              // [768][768] bf16
    short* qnat = Wpb + WN;                                 // [MROWS][2304] bf16
    short* xb   = qnat + (size_t)MROWS * QKVC;              // [MROWS][768] bf16
    short* aout = xb;                                       // ALIAS: xb dead after gemm0
    short* vtb  = xb + (size_t)MROWS * EMB;                 // [B][H][HD][640] bf16
    short* bexp = vtb + (size_t)BATCH * NHEAD * HD * NPAD;  // [H][640][640] bf16 (q-major)

    const int XN = MROWS * EMB;  // 14180352
    cast_f32_bf16<<<576, 256, 0, stream>>>(Wq, Wb, (int)WN);
    cast_f32_bf16<<<576, 256, 0, stream>>>(Wk, Wb + WN, (int)WN);
    cast_f32_bf16<<<576, 256, 0, stream>>>(Wv, Wb + 2 * WN, (int)WN);
    cast_f32_bf16<<<576, 256, 0, stream>>>(Wp, Wpb, (int)WN);
    cast_f32_bf16<<<13848, 256, 0, stream>>>(x, xb, XN);
    bias_expand<<<NPAD, NPAD, 0, stream>>>(rel, bexp);

    gemm_bt<0><<<dim3(18, 145), 256, 0, stream>>>(xb, Wb, bq, bk, bv, qnat, MROWS);
    transpose_v<<<BATCH * NHEAD * NKT, 256, 0, stream>>>(qnat, vtb);
    attn_kernel<<<BATCH * NHEAD * NQT, 512, 0, stream>>>(qnat, vtb, bexp, aout);
    gemm_bt<1><<<dim3(6, 145), 256, 0, stream>>>(aout, Wpb, bp, bp, bp, d_out, MROWS);
}

// Round 7
// 315.739 us; speedup vs baseline: 1.2412x; 1.1093x over previous
//
#include <hip/hip_runtime.h>
#include <stdint.h>

#define HGT   24
#define WID   24
#define NHEAD 12
#define EMB   768
#define HD    64
#define NGRID 576
#define NTOK  577
#define NPAD  640              // padded token dim (10 tiles of 64)
#define BATCH 32
#define MROWS (BATCH * NTOK)   // 18464
#define NKT   10
#define NQT   5                // 5 q-tiles of 128
#define QKVC  (3 * EMB)        // 2304

typedef __attribute__((ext_vector_type(8))) short bf16x8;
typedef __attribute__((ext_vector_type(4))) float f32x4;

__device__ __forceinline__ short f2bf(float f) {
    union { float f; unsigned u; } c; c.f = f;
    unsigned r = (c.u + 0x7FFFu + ((c.u >> 16) & 1u)) >> 16;
    return (short)(r & 0xFFFFu);
}
__device__ __forceinline__ float b2f(short s) {
    union { unsigned u; float f; } c; c.u = ((unsigned)(unsigned short)s) << 16;
    return c.f;
}

// async global->LDS, 16B per lane; LDS dest = wave-uniform base + lane*16
__device__ __forceinline__ void gload16(void* lds, const void* g) {
    __builtin_amdgcn_global_load_lds(
        (const __attribute__((address_space(1))) void*)g,
        (__attribute__((address_space(3))) void*)lds, 16, 0, 0);
}

__device__ __forceinline__ void wait_vm0_barrier() {
    asm volatile("s_waitcnt vmcnt(0)" ::: "memory");
    __builtin_amdgcn_s_barrier();
}

// bijective XCD-chunk swizzle (m204): orig -> wgid so each XCD gets a contiguous chunk
__device__ __forceinline__ int xcd_swizzle(int orig, int nwg) {
    int q = nwg >> 3, r = nwg & 7;
    int xcd = orig & 7, idx = orig >> 3;
    return (xcd < r) ? xcd * (q + 1) + idx : r * (q + 1) + (xcd - r) * q + idx;
}

// ---------------------------------------------------------------- cast f32->bf16
__global__ void cast_f32_bf16(const float* __restrict__ src, short* __restrict__ dst, int n) {
    int i = (blockIdx.x * blockDim.x + threadIdx.x) * 4;
    int stride = gridDim.x * blockDim.x * 4;
    for (int j = i; j < n; j += stride) {
        float4 v = *(const float4*)(src + j);
        short4 o;
        o.x = f2bf(v.x); o.y = f2bf(v.y); o.z = f2bf(v.z); o.w = f2bf(v.w);
        *(short4*)(dst + j) = o;
    }
}

// ---------------------------------------------------------------- bias table bf16 [H][q 640][k 640]
__global__ void bias_expand(const float* __restrict__ rel, short* __restrict__ be) {
    int q = blockIdx.x;     // query 0..639
    int k = threadIdx.x;    // key   0..639
    float v[NHEAD];
    if (k >= NTOK) {
#pragma unroll
        for (int h = 0; h < NHEAD; h++) v[h] = -1e30f;
    } else if (q == 0 || q >= NTOK || k == 0) {
#pragma unroll
        for (int h = 0; h < NHEAD; h++) v[h] = 0.f;
    } else {
        int i = q - 1, j = k - 1;
        int idx = ((i / WID) - (j / WID) + HGT - 1) * (2 * WID - 1)
                + ((i % WID) - (j % WID) + WID - 1);
        const float* rp = rel + (size_t)idx * NHEAD;
#pragma unroll
        for (int h = 0; h < NHEAD; h++) v[h] = rp[h];
    }
#pragma unroll
    for (int h = 0; h < NHEAD; h++)
        be[((size_t)h * NPAD + q) * NPAD + k] = f2bf(v[h]);
}

// ---------------------------------------------------------------- V transpose from qnat: vt[b][h][d][key(640)]
__global__ __launch_bounds__(256) void transpose_v(const short* __restrict__ qnat, short* __restrict__ vt) {
    __shared__ __align__(16) short T[64][72];
    int bi = blockIdx.x;
    int kt = bi % NKT;
    int h  = (bi / NKT) % NHEAD;
    int b  = bi / (NKT * NHEAD);
    int t  = threadIdx.x;

    int r  = t >> 2, cb = (t & 3) * 16;
    int key = kt * 64 + r; if (key >= NTOK) key = NTOK - 1;
    const short* src = qnat + (size_t)(b * NTOK + key) * QKVC + 2 * EMB + h * HD;
    *(int4*)&T[r][cb]     = *(const int4*)(src + cb);
    *(int4*)&T[r][cb + 8] = *(const int4*)(src + cb + 8);
    __syncthreads();

    int d = t >> 2, kb = (t & 3) * 16;
    short tmp[16];
#pragma unroll
    for (int s = 0; s < 16; s++) tmp[s] = T[kb + s][d];
    short* dst = vt + (((size_t)b * NHEAD + h) * HD + d) * NPAD + kt * 64 + kb;
    *(int4*)&dst[0] = *(int4*)&tmp[0];
    *(int4*)&dst[8] = *(int4*)&tmp[8];
}

// ---------------------------------------------------------------- GEMM  C = A @ B^T (+bias)
// BK=128, single 64KB LDS buffer, 6 K-steps. 1D grid + bijective XCD swizzle.
// MODE 0: NC=2304, bf16 out -> qnat[m][2304]; MODE 1: NC=768, f32 out + b0
template <int MODE>
__global__ __launch_bounds__(256) void gemm_bt(
    const short* __restrict__ A, const short* __restrict__ Bw,
    const float* __restrict__ b0, const float* __restrict__ b1, const float* __restrict__ b2,
    void* __restrict__ Outp, int M)
{
    constexpr int NC  = (MODE == 0) ? QKVC : EMB;
    constexpr int NBX = NC / 128;     // 18 or 6
    constexpr int K   = EMB;          // 768
    constexpr int NST = K / 128;      // 6

    __shared__ __align__(16) short Asl[128][128];
    __shared__ __align__(16) short Bsl[128][128];

    const int t    = threadIdx.x;
    const int lane = t & 63;
    const int w    = t >> 6;
    const int wr   = (w >> 1) * 64;
    const int wc   = (w & 1) * 64;
    const int lg   = lane >> 4;
    const int li   = lane & 15;

    const int nwg  = NBX * 145;
    const int wgid = xcd_swizzle(blockIdx.x, nwg);
    const int tm   = (wgid / NBX) * 128;
    const int tn   = (wgid % NBX) * 128;

    // staging: 8 issues per matrix; issue p covers rows p*16..p*16+15.
    // wave w writes rows p*16+w*4..+3; lane l -> row p*16+w*4+(l>>4), phys chunk l&15.
    // source holds logical chunk (l&15)^(row&15); row&15 = w*4+(l>>4).
    const int srow16 = w * 4 + (lane >> 4);                 // 0..15
    const int cofs   = ((lane & 15) ^ srow16) * 8;          // shorts

    const short* ag[8];
    const short* bg[8];
#pragma unroll
    for (int p = 0; p < 8; p++) {
        int rm = tm + p * 16 + srow16; if (rm >= M) rm = M - 1;
        ag[p] = A  + (size_t)rm * K + cofs;
        bg[p] = Bw + (size_t)(tn + p * 16 + srow16) * K + cofs;
    }

    f32x4 acc[4][4];
#pragma unroll
    for (int i = 0; i < 4; i++)
#pragma unroll
        for (int j = 0; j < 4; j++) acc[i][j] = (f32x4){0.f, 0.f, 0.f, 0.f};

    // prologue: stage step 0
#pragma unroll
    for (int p = 0; p < 8; p++) {
        gload16(&Asl[p * 16 + w * 4][0], ag[p]);
        gload16(&Bsl[p * 16 + w * 4][0], bg[p]);
    }

    for (int step = 0; step < NST; step++) {
        wait_vm0_barrier();    // tile landed (each wave waits own loads, barrier syncs)

#pragma unroll
        for (int kk = 0; kk < 4; kk++) {
            bf16x8 af[4], bfr[4];
#pragma unroll
            for (int i = 0; i < 4; i++)
                af[i]  = *(const bf16x8*)&Asl[wr + i * 16 + li][((kk * 4 + lg) ^ li) * 8];
#pragma unroll
            for (int j = 0; j < 4; j++)
                bfr[j] = *(const bf16x8*)&Bsl[wc + j * 16 + li][((kk * 4 + lg) ^ li) * 8];
#pragma unroll
            for (int i = 0; i < 4; i++)
#pragma unroll
                for (int j = 0; j < 4; j++)
                    acc[i][j] = __builtin_amdgcn_mfma_f32_16x16x32_bf16(af[i], bfr[j], acc[i][j], 0, 0, 0);
        }

        __builtin_amdgcn_s_barrier();   // all waves done reading this tile
        if (step + 1 < NST) {
            int k0 = (step + 1) * 128;
#pragma unroll
            for (int p = 0; p < 8; p++) {
                gload16(&Asl[p * 16 + w * 4][0], ag[p] + k0);
                gload16(&Bsl[p * 16 + w * 4][0], bg[p] + k0);
            }
        }
    }

    // epilogue: natural layout
#pragma unroll
    for (int j = 0; j < 4; j++) {
        int c = tn + wc + j * 16 + li;
        float bias;
        if constexpr (MODE == 0) {
            int which = (c >= 2 * EMB) ? 2 : ((c >= EMB) ? 1 : 0);
            const float* bb = (which == 0) ? b0 : ((which == 1) ? b1 : b2);
            bias = bb[c - which * EMB];
        } else {
            bias = b0[c];
        }
#pragma unroll
        for (int i = 0; i < 4; i++) {
#pragma unroll
            for (int r = 0; r < 4; r++) {
                int m = tm + wr + i * 16 + lg * 4 + r;
                if (m >= M) continue;
                float v = acc[i][j][r] + bias;
                if constexpr (MODE == 0)
                    ((short*)Outp)[(size_t)m * NC + c] = f2bf(v);
                else
                    ((float*)Outp)[(size_t)m * NC + c] = v;
            }
        }
    }
}

// ---------------------------------------------------------------- flash attention (swapped QK^T)
// 512 threads (8 waves x 16 queries = 128 q per block); h-major block order + XCD chunk swizzle
__global__ __launch_bounds__(512) void attn_kernel(
    const short* __restrict__ qnat, const short* __restrict__ vt,
    const short* __restrict__ biasx, short* __restrict__ aout)
{
    __shared__ __align__(16) short Ksl[2][64][64];
    __shared__ __align__(16) short Vsl[2][64][64];   // [d][key_local]
    __shared__ __align__(16) short Psl[8][16][72];   // [wave][q(li)][key]

    // chunked swizzle (1920 % 8 == 0) + h-major decomposition
    const int wg = (blockIdx.x & 7) * (BATCH * NHEAD * NQT / 8) + (blockIdx.x >> 3);
    const int qt = wg % NQT;
    const int rest = wg / NQT;        // 0..383
    const int b  = rest & 31;
    const int h  = rest >> 5;

    const int t    = threadIdx.x;
    const int lane = t & 63;
    const int w    = t >> 6;          // 0..7
    const int lg   = lane >> 4;
    const int li   = lane & 15;
    const int xh   = li & 7;
    const int qbase = qt * 128;
    const int myq  = qbase + w * 16 + li;   // this lane's query column

    const short* qp  = qnat + (size_t)b * NTOK * QKVC + h * HD;          // + n*QKVC
    const short* kp  = qp + EMB;
    const short* vtp = vt + ((size_t)b * NHEAD + h) * (size_t)HD * NPAD;
    const short* browq = biasx + ((size_t)h * NPAD + myq) * NPAD;        // [k] bf16

    bf16x8 qf[2];   // B-fragment: Q[myq][k]
    {
        int qrow = myq < NTOK ? myq : NTOK - 1;
        qf[0] = *(const bf16x8*)(qp + (size_t)qrow * QKVC + lg * 8);
        qf[1] = *(const bf16x8*)(qp + (size_t)qrow * QKVC + 32 + lg * 8);
    }

    float mrun = -1e30f, lrun = 0.f;
    f32x4 oacc[4];
#pragma unroll
    for (int d = 0; d < 4; d++) oacc[d] = (f32x4){0.f, 0.f, 0.f, 0.f};

    const int srow = w * 8 + (lane >> 3);
    const int cofs = ((lane & 7) ^ (lane >> 3)) * 8;

    {
        int key = srow; if (key >= NTOK) key = NTOK - 1;
        gload16(&Ksl[0][w * 8][0], kp + (size_t)key * QKVC + cofs);
        gload16(&Vsl[0][w * 8][0], vtp + (size_t)srow * NPAD + cofs);
    }
    wait_vm0_barrier();

    short (*Kc)[64] = Ksl[0], (*Kn)[64] = Ksl[1];
    short (*Vc)[64] = Vsl[0], (*Vn)[64] = Vsl[1];

    for (int kt = 0; kt < NKT; kt++) {
        if (kt + 1 < NKT) {
            int key = (kt + 1) * 64 + srow; if (key >= NTOK) key = NTOK - 1;
            gload16(&Kn[w * 8][0], kp + (size_t)key * QKVC + cofs);
            gload16(&Vn[w * 8][0], vtp + (size_t)srow * NPAD + (kt + 1) * 64 + cofs);
        }

        // S^T = K @ Q^T + bias^T
        float pvv[4][4];
        __builtin_amdgcn_s_setprio(1);
#pragma unroll
        for (int j = 0; j < 4; j++) {
            short4 bs = *(const short4*)&browq[kt * 64 + j * 16 + lg * 4];
            bf16x8 ak0 = *(const bf16x8*)&Kc[j * 16 + li][(lg ^ xh) * 8];
            bf16x8 ak1 = *(const bf16x8*)&Kc[j * 16 + li][((4 + lg) ^ xh) * 8];
            f32x4 s = (f32x4){0.f, 0.f, 0.f, 0.f};
            s = __builtin_amdgcn_mfma_f32_16x16x32_bf16(ak0, qf[0], s, 0, 0, 0);
            s = __builtin_amdgcn_mfma_f32_16x16x32_bf16(ak1, qf[1], s, 0, 0, 0);
            pvv[j][0] = fmaf(s[0], 0.125f, b2f(bs.x));
            pvv[j][1] = fmaf(s[1], 0.125f, b2f(bs.y));
            pvv[j][2] = fmaf(s[2], 0.125f, b2f(bs.z));
            pvv[j][3] = fmaf(s[3], 0.125f, b2f(bs.w));
        }
        __builtin_amdgcn_s_setprio(0);

        // online softmax: one query per lane; reduce across the 4 lg-lanes
        float mt = pvv[0][0];
#pragma unroll
        for (int j = 0; j < 4; j++)
#pragma unroll
            for (int r = 0; r < 4; r++) mt = fmaxf(mt, pvv[j][r]);
        mt = fmaxf(mt, __shfl_xor(mt, 16, 64));
        mt = fmaxf(mt, __shfl_xor(mt, 32, 64));
        float nm  = fmaxf(mrun, mt);
        float fac = __expf(mrun - nm);
        float rs  = 0.f;
#pragma unroll
        for (int j = 0; j < 4; j++)
#pragma unroll
            for (int r = 0; r < 4; r++) {
                float p = __expf(pvv[j][r] - nm);
                pvv[j][r] = p;
                rs += p;
            }
        rs += __shfl_xor(rs, 16, 64);
        rs += __shfl_xor(rs, 32, 64);
        lrun = lrun * fac + rs;
        mrun = nm;
#pragma unroll
        for (int d = 0; d < 4; d++) oacc[d] *= fac;

        // P^T -> Psl[w][q=li][key] (wave-private, vectorized short4)
#pragma unroll
        for (int j = 0; j < 4; j++) {
            short4 ps;
            ps.x = f2bf(pvv[j][0]); ps.y = f2bf(pvv[j][1]);
            ps.z = f2bf(pvv[j][2]); ps.w = f2bf(pvv[j][3]);
            *(short4*)&Psl[w][li][j * 16 + lg * 4] = ps;
        }

        // O^T += V^T @ P^T
        __builtin_amdgcn_s_setprio(1);
#pragma unroll
        for (int dd = 0; dd < 4; dd++) {
#pragma unroll
            for (int kk = 0; kk < 2; kk++) {
                bf16x8 av = *(const bf16x8*)&Vc[dd * 16 + li][((kk * 4 + lg) ^ xh) * 8];
                bf16x8 pb = *(const bf16x8*)&Psl[w][li][kk * 32 + lg * 8];
                oacc[dd] = __builtin_amdgcn_mfma_f32_16x16x32_bf16(av, pb, oacc[dd], 0, 0, 0);
            }
        }
        __builtin_amdgcn_s_setprio(0);

        wait_vm0_barrier();
        short (*tp)[64];
        tp = Kc; Kc = Kn; Kn = tp;
        tp = Vc; Vc = Vn; Vn = tp;
    }

    // epilogue: O[q][d] = O^T[d][q]/l ; vectorized short4 stores
    if (myq < NTOK) {
        float inv = 1.0f / lrun;
        short* op = aout + ((size_t)b * NTOK + myq) * EMB + h * HD;
#pragma unroll
        for (int dd = 0; dd < 4; dd++) {
            short4 o;
            o.x = f2bf(oacc[dd][0] * inv);
            o.y = f2bf(oacc[dd][1] * inv);
            o.z = f2bf(oacc[dd][2] * inv);
            o.w = f2bf(oacc[dd][3] * inv);
            *(short4*)&op[dd * 16 + lg * 4] = o;
        }
    }
}

// ---------------------------------------------------------------- launch
extern "C" void kernel_launch(void* const* d_in, const int* in_sizes, int n_in,
                              void* d_out, int out_size, void* d_ws, size_t ws_size,
                              hipStream_t stream) {
    (void)in_sizes; (void)n_in; (void)out_size; (void)ws_size;
    const float* x   = (const float*)d_in[0];
    const float* Wq  = (const float*)d_in[1];
    const float* bq  = (const float*)d_in[2];
    const float* Wk  = (const float*)d_in[3];
    const float* bk  = (const float*)d_in[4];
    const float* Wv  = (const float*)d_in[5];
    const float* bv  = (const float*)d_in[6];
    const float* Wp  = (const float*)d_in[7];
    const float* bp  = (const float*)d_in[8];
    const float* rel = (const float*)d_in[9];

    const size_t WN = (size_t)EMB * EMB;                    // 589824
    short* Wb   = (short*)d_ws;                             // [2304][768] bf16
    short* Wpb  = Wb + 3 * WN;                              // [768][768] bf16
    short* qnat = Wpb + WN;                                 // [MROWS][2304] bf16
    short* xb   = qnat + (size_t)MROWS * QKVC;              // [MROWS][768] bf16
    short* aout = xb;                                       // ALIAS: xb dead after gemm0
    short* vtb  = xb + (size_t)MROWS * EMB;                 // [B][H][HD][640] bf16
    short* bexp = vtb + (size_t)BATCH * NHEAD * HD * NPAD;  // [H][640][640] bf16 (q-major)

    const int XN = MROWS * EMB;  // 14180352
    cast_f32_bf16<<<576, 256, 0, stream>>>(Wq, Wb, (int)WN);
    cast_f32_bf16<<<576, 256, 0, stream>>>(Wk, Wb + WN, (int)WN);
    cast_f32_bf16<<<576, 256, 0, stream>>>(Wv, Wb + 2 * WN, (int)WN);
    cast_f32_bf16<<<576, 256, 0, stream>>>(Wp, Wpb, (int)WN);
    cast_f32_bf16<<<13848, 256, 0, stream>>>(x, xb, XN);
    bias_expand<<<NPAD, NPAD, 0, stream>>>(rel, bexp);

    gemm_bt<0><<<18 * 145, 256, 0, stream>>>(xb, Wb, bq, bk, bv, qnat, MROWS);
    transpose_v<<<BATCH * NHEAD * NKT, 256, 0, stream>>>(qnat, vtb);
    attn_kernel<<<BATCH * NHEAD * NQT, 512, 0, stream>>>(qnat, vtb, bexp, aout);
    gemm_bt<1><<<6 * 145, 256, 0, stream>>>(aout, Wpb, bp, bp, bp, d_out, MROWS);
}

// Round 8
// 301.686 us; speedup vs baseline: 1.2990x; 1.0466x over previous
//
#include <hip/hip_runtime.h>
#include <stdint.h>

#define HGT   24
#define WID   24
#define NHEAD 12
#define EMB   768
#define HD    64
#define NGRID 576
#define NTOK  577
#define NPAD  640              // padded token dim (10 tiles of 64)
#define BATCH 32
#define MROWS (BATCH * NTOK)   // 18464
#define NKT   10
#define NQT   5                // 5 q-tiles of 128
#define QKVC  (3 * EMB)        // 2304

typedef __attribute__((ext_vector_type(8))) short bf16x8;
typedef __attribute__((ext_vector_type(4))) float f32x4;

__device__ __forceinline__ short f2bf(float f) {
    union { float f; unsigned u; } c; c.f = f;
    unsigned r = (c.u + 0x7FFFu + ((c.u >> 16) & 1u)) >> 16;
    return (short)(r & 0xFFFFu);
}
__device__ __forceinline__ float b2f(short s) {
    union { unsigned u; float f; } c; c.u = ((unsigned)(unsigned short)s) << 16;
    return c.f;
}

// async global->LDS, 16B per lane; LDS dest = wave-uniform base + lane*16
__device__ __forceinline__ void gload16(void* lds, const void* g) {
    __builtin_amdgcn_global_load_lds(
        (const __attribute__((address_space(1))) void*)g,
        (__attribute__((address_space(3))) void*)lds, 16, 0, 0);
}

__device__ __forceinline__ void wait_vm0_barrier() {
    asm volatile("s_waitcnt vmcnt(0)" ::: "memory");
    __builtin_amdgcn_s_barrier();
}

// bijective XCD-chunk swizzle (m204)
__device__ __forceinline__ int xcd_swizzle(int orig, int nwg) {
    int q = nwg >> 3, r = nwg & 7;
    int xcd = orig & 7, idx = orig >> 3;
    return (xcd < r) ? xcd * (q + 1) + idx : r * (q + 1) + (xcd - r) * q + idx;
}

// ---------------------------------------------------------------- cast f32->bf16
__global__ void cast_f32_bf16(const float* __restrict__ src, short* __restrict__ dst, int n) {
    int i = (blockIdx.x * blockDim.x + threadIdx.x) * 4;
    int stride = gridDim.x * blockDim.x * 4;
    for (int j = i; j < n; j += stride) {
        float4 v = *(const float4*)(src + j);
        short4 o;
        o.x = f2bf(v.x); o.y = f2bf(v.y); o.z = f2bf(v.z); o.w = f2bf(v.w);
        *(short4*)(dst + j) = o;
    }
}

// ---------------------------------------------------------------- bias table bf16 [H][q 640][k 640]
__global__ void bias_expand(const float* __restrict__ rel, short* __restrict__ be) {
    int q = blockIdx.x;     // query 0..639
    int k = threadIdx.x;    // key   0..639
    float v[NHEAD];
    if (k >= NTOK) {
#pragma unroll
        for (int h = 0; h < NHEAD; h++) v[h] = -1e30f;
    } else if (q == 0 || q >= NTOK || k == 0) {
#pragma unroll
        for (int h = 0; h < NHEAD; h++) v[h] = 0.f;
    } else {
        int i = q - 1, j = k - 1;
        int idx = ((i / WID) - (j / WID) + HGT - 1) * (2 * WID - 1)
                + ((i % WID) - (j % WID) + WID - 1);
        const float* rp = rel + (size_t)idx * NHEAD;
#pragma unroll
        for (int h = 0; h < NHEAD; h++) v[h] = rp[h];
    }
#pragma unroll
    for (int h = 0; h < NHEAD; h++)
        be[((size_t)h * NPAD + q) * NPAD + k] = f2bf(v[h]);
}

// ---------------------------------------------------------------- V transpose from qnat: vt[b][h][d][key(640)]
__global__ __launch_bounds__(256) void transpose_v(const short* __restrict__ qnat, short* __restrict__ vt) {
    __shared__ __align__(16) short T[64][72];
    int bi = blockIdx.x;
    int kt = bi % NKT;
    int h  = (bi / NKT) % NHEAD;
    int b  = bi / (NKT * NHEAD);
    int t  = threadIdx.x;

    int r  = t >> 2, cb = (t & 3) * 16;
    int key = kt * 64 + r; if (key >= NTOK) key = NTOK - 1;
    const short* src = qnat + (size_t)(b * NTOK + key) * QKVC + 2 * EMB + h * HD;
    *(int4*)&T[r][cb]     = *(const int4*)(src + cb);
    *(int4*)&T[r][cb + 8] = *(const int4*)(src + cb + 8);
    __syncthreads();

    int d = t >> 2, kb = (t & 3) * 16;
    short tmp[16];
#pragma unroll
    for (int s = 0; s < 16; s++) tmp[s] = T[kb + s][d];
    short* dst = vt + (((size_t)b * NHEAD + h) * HD + d) * NPAD + kt * 64 + kb;
    *(int4*)&dst[0] = *(int4*)&tmp[0];
    *(int4*)&dst[8] = *(int4*)&tmp[8];
}

// ---------------------------------------------------------------- GEMM  C = A @ B^T (+bias)
// 256x256 tile, BK=64, 8 waves (512 thr), 4-phase-per-K-tile schedule with
// counted vmcnt (T3+T4) + setprio (T5) + XOR LDS swizzle (T2) + XCD swizzle (T1).
// MODE 0: NC=2304, bf16 out -> qnat[m][2304]; MODE 1: NC=768, f32 out + b0
template <int MODE>
__global__ __launch_bounds__(512) void gemm_bt(
    const short* __restrict__ A, const short* __restrict__ Bw,
    const float* __restrict__ b0, const float* __restrict__ b1, const float* __restrict__ b2,
    void* __restrict__ Outp, int M)
{
    constexpr int NC  = (MODE == 0) ? QKVC : EMB;
    constexpr int NBX = NC / 256;     // 9 or 3
    constexpr int K   = EMB;          // 768
    constexpr int NT  = K / 64;       // 12 K-tiles

    __shared__ __align__(16) short Asl[2][256][64];   // 64 KB
    __shared__ __align__(16) short Bsl[2][256][64];   // 64 KB

    const int t    = threadIdx.x;
    const int lane = t & 63;
    const int w    = t >> 6;          // 0..7
    const int wm   = w >> 2;          // 0..1  (M half)
    const int wn   = w & 3;           // 0..3  (N quarter)
    const int lg   = lane >> 4;
    const int li   = lane & 15;
    const int xh   = li & 7;

    const int nwg  = NBX * ((MROWS + 255) / 256);     // 9*73 or 3*73
    const int wgid = xcd_swizzle(blockIdx.x, nwg);
    const int tm   = (wgid / NBX) * 256;
    const int tn   = (wgid % NBX) * 256;

    // staging: one gload instr = 512 lanes x 16B = 64 rows. wave w covers rows
    // +w*8..+7 of the issue block; lane l -> row w*8+(l>>3), phys chunk l&7.
    // source pre-swizzled: logical chunk (l&7)^(row&7).
    const int srow = w * 8 + (lane >> 3);             // 0..63
    const int cofs = ((lane & 7) ^ (lane >> 3)) * 8;  // shorts

    // issue-block row offsets. A ordered {0,128,64,192} so both wm-halves'
    // early rows (phases 0-1) land in the first two A issues.
    constexpr int AOFF[4] = {0, 128, 64, 192};
    constexpr int BOFF[4] = {0, 64, 128, 192};

    const short* agp[4];
    const short* bgp[4];
#pragma unroll
    for (int i = 0; i < 4; i++) {
        int ra = tm + AOFF[i] + srow; if (ra >= M) ra = M - 1;
        agp[i] = A  + (size_t)ra * K + cofs;
        bgp[i] = Bw + (size_t)(tn + BOFF[i] + srow) * K + cofs;
    }

    f32x4 acc[8][4];
#pragma unroll
    for (int i = 0; i < 8; i++)
#pragma unroll
        for (int j = 0; j < 4; j++) acc[i][j] = (f32x4){0.f, 0.f, 0.f, 0.f};

    // prologue: stage tile 0 into buf 0 (queue order: B0..3, A0..3)
#pragma unroll
    for (int i = 0; i < 4; i++) gload16(&Bsl[0][BOFF[i] + w * 8][0], bgp[i]);
#pragma unroll
    for (int i = 0; i < 4; i++) gload16(&Asl[0][AOFF[i] + w * 8][0], agp[i]);
    asm volatile("s_waitcnt vmcnt(2)" ::: "memory");   // B0..3 + A0,A1 landed
    __builtin_amdgcn_s_barrier();

    for (int kt = 0; kt < NT; kt++) {
        const int c = kt & 1, nb = c ^ 1;
        const bool more = (kt + 1 < NT);
        const int k0n = (kt + 1) * 64;

        bf16x8 bf[4][2];
#pragma unroll
        for (int q = 0; q < 4; q++) {
            // ds-read this phase's A fragments (mi = 2q, 2q+1)
            bf16x8 af[2][2];
#pragma unroll
            for (int mm = 0; mm < 2; mm++)
#pragma unroll
                for (int kk = 0; kk < 2; kk++)
                    af[mm][kk] = *(const bf16x8*)
                        &Asl[c][wm * 128 + (q * 2 + mm) * 16 + li][((kk * 4 + lg) ^ xh) * 8];
            if (q == 0) {
                // B fragments for the whole K-tile (reused by all 4 phases)
#pragma unroll
                for (int nj = 0; nj < 4; nj++)
#pragma unroll
                    for (int kk = 0; kk < 2; kk++)
                        bf[nj][kk] = *(const bf16x8*)
                            &Bsl[c][wn * 64 + nj * 16 + li][((kk * 4 + lg) ^ xh) * 8];
            }

            // stage next tile (2 issues/phase) + counted waits
            if (q == 0) {
                if (more) {
                    gload16(&Bsl[nb][BOFF[0] + w * 8][0], bgp[0] + k0n);
                    gload16(&Bsl[nb][BOFF[1] + w * 8][0], bgp[1] + k0n);
                }
            } else if (q == 1) {
                if (more) {
                    gload16(&Bsl[nb][BOFF[2] + w * 8][0], bgp[2] + k0n);
                    gload16(&Bsl[nb][BOFF[3] + w * 8][0], bgp[3] + k0n);
                    asm volatile("s_waitcnt vmcnt(4)" ::: "memory");  // this tile's A2,A3 landed
                } else {
                    asm volatile("s_waitcnt vmcnt(0)" ::: "memory");
                }
            } else if (q == 2) {
                if (more) {
                    gload16(&Asl[nb][AOFF[0] + w * 8][0], agp[0] + k0n);
                    gload16(&Asl[nb][AOFF[1] + w * 8][0], agp[1] + k0n);
                }
            } else {
                if (more) {
                    gload16(&Asl[nb][AOFF[2] + w * 8][0], agp[2] + k0n);
                    gload16(&Asl[nb][AOFF[3] + w * 8][0], agp[3] + k0n);
                    asm volatile("s_waitcnt vmcnt(2)" ::: "memory");  // next tile's B + A0,A1 landed
                }
            }
            __builtin_amdgcn_s_barrier();

            __builtin_amdgcn_s_setprio(1);
#pragma unroll
            for (int mm = 0; mm < 2; mm++)
#pragma unroll
                for (int nj = 0; nj < 4; nj++)
#pragma unroll
                    for (int kk = 0; kk < 2; kk++)
                        acc[q * 2 + mm][nj] = __builtin_amdgcn_mfma_f32_16x16x32_bf16(
                            af[mm][kk], bf[nj][kk], acc[q * 2 + mm][nj], 0, 0, 0);
            __builtin_amdgcn_s_setprio(0);
            __builtin_amdgcn_s_barrier();
        }
    }

    // epilogue
#pragma unroll
    for (int nj = 0; nj < 4; nj++) {
        int cc = tn + wn * 64 + nj * 16 + li;
        float bias;
        if constexpr (MODE == 0) {
            int which = (cc >= 2 * EMB) ? 2 : ((cc >= EMB) ? 1 : 0);
            const float* bb = (which == 0) ? b0 : ((which == 1) ? b1 : b2);
            bias = bb[cc - which * EMB];
        } else {
            bias = b0[cc];
        }
#pragma unroll
        for (int mi = 0; mi < 8; mi++) {
#pragma unroll
            for (int r = 0; r < 4; r++) {
                int m = tm + wm * 128 + mi * 16 + lg * 4 + r;
                if (m >= M) continue;
                float v = acc[mi][nj][r] + bias;
                if constexpr (MODE == 0)
                    ((short*)Outp)[(size_t)m * NC + cc] = f2bf(v);
                else
                    ((float*)Outp)[(size_t)m * NC + cc] = v;
            }
        }
    }
}

// ---------------------------------------------------------------- flash attention (swapped QK^T)
// 512 threads (8 waves x 16 queries = 128 q per block); h-major block order + XCD chunk swizzle
__global__ __launch_bounds__(512) void attn_kernel(
    const short* __restrict__ qnat, const short* __restrict__ vt,
    const short* __restrict__ biasx, short* __restrict__ aout)
{
    __shared__ __align__(16) short Ksl[2][64][64];
    __shared__ __align__(16) short Vsl[2][64][64];   // [d][key_local]
    __shared__ __align__(16) short Psl[8][16][72];   // [wave][q(li)][key]

    // chunked swizzle (1920 % 8 == 0) + h-major decomposition
    const int wg = (blockIdx.x & 7) * (BATCH * NHEAD * NQT / 8) + (blockIdx.x >> 3);
    const int qt = wg % NQT;
    const int rest = wg / NQT;        // 0..383
    const int b  = rest & 31;
    const int h  = rest >> 5;

    const int t    = threadIdx.x;
    const int lane = t & 63;
    const int w    = t >> 6;          // 0..7
    const int lg   = lane >> 4;
    const int li   = lane & 15;
    const int xh   = li & 7;
    const int qbase = qt * 128;
    const int myq  = qbase + w * 16 + li;   // this lane's query column

    const short* qp  = qnat + (size_t)b * NTOK * QKVC + h * HD;          // + n*QKVC
    const short* kp  = qp + EMB;
    const short* vtp = vt + ((size_t)b * NHEAD + h) * (size_t)HD * NPAD;
    const short* browq = biasx + ((size_t)h * NPAD + myq) * NPAD;        // [k] bf16

    bf16x8 qf[2];   // B-fragment: Q[myq][k]
    {
        int qrow = myq < NTOK ? myq : NTOK - 1;
        qf[0] = *(const bf16x8*)(qp + (size_t)qrow * QKVC + lg * 8);
        qf[1] = *(const bf16x8*)(qp + (size_t)qrow * QKVC + 32 + lg * 8);
    }

    float mrun = -1e30f, lrun = 0.f;
    f32x4 oacc[4];
#pragma unroll
    for (int d = 0; d < 4; d++) oacc[d] = (f32x4){0.f, 0.f, 0.f, 0.f};

    const int srow = w * 8 + (lane >> 3);
    const int cofs = ((lane & 7) ^ (lane >> 3)) * 8;

    {
        int key = srow; if (key >= NTOK) key = NTOK - 1;
        gload16(&Ksl[0][w * 8][0], kp + (size_t)key * QKVC + cofs);
        gload16(&Vsl[0][w * 8][0], vtp + (size_t)srow * NPAD + cofs);
    }
    wait_vm0_barrier();

    short (*Kc)[64] = Ksl[0], (*Kn)[64] = Ksl[1];
    short (*Vc)[64] = Vsl[0], (*Vn)[64] = Vsl[1];

    for (int kt = 0; kt < NKT; kt++) {
        if (kt + 1 < NKT) {
            int key = (kt + 1) * 64 + srow; if (key >= NTOK) key = NTOK - 1;
            gload16(&Kn[w * 8][0], kp + (size_t)key * QKVC + cofs);
            gload16(&Vn[w * 8][0], vtp + (size_t)srow * NPAD + (kt + 1) * 64 + cofs);
        }

        // S^T = K @ Q^T + bias^T
        float pvv[4][4];
        __builtin_amdgcn_s_setprio(1);
#pragma unroll
        for (int j = 0; j < 4; j++) {
            short4 bs = *(const short4*)&browq[kt * 64 + j * 16 + lg * 4];
            bf16x8 ak0 = *(const bf16x8*)&Kc[j * 16 + li][(lg ^ xh) * 8];
            bf16x8 ak1 = *(const bf16x8*)&Kc[j * 16 + li][((4 + lg) ^ xh) * 8];
            f32x4 s = (f32x4){0.f, 0.f, 0.f, 0.f};
            s = __builtin_amdgcn_mfma_f32_16x16x32_bf16(ak0, qf[0], s, 0, 0, 0);
            s = __builtin_amdgcn_mfma_f32_16x16x32_bf16(ak1, qf[1], s, 0, 0, 0);
            pvv[j][0] = fmaf(s[0], 0.125f, b2f(bs.x));
            pvv[j][1] = fmaf(s[1], 0.125f, b2f(bs.y));
            pvv[j][2] = fmaf(s[2], 0.125f, b2f(bs.z));
            pvv[j][3] = fmaf(s[3], 0.125f, b2f(bs.w));
        }
        __builtin_amdgcn_s_setprio(0);

        // online softmax: one query per lane; reduce across the 4 lg-lanes
        float mt = pvv[0][0];
#pragma unroll
        for (int j = 0; j < 4; j++)
#pragma unroll
            for (int r = 0; r < 4; r++) mt = fmaxf(mt, pvv[j][r]);
        mt = fmaxf(mt, __shfl_xor(mt, 16, 64));
        mt = fmaxf(mt, __shfl_xor(mt, 32, 64));
        float nm  = fmaxf(mrun, mt);
        float fac = __expf(mrun - nm);
        float rs  = 0.f;
#pragma unroll
        for (int j = 0; j < 4; j++)
#pragma unroll
            for (int r = 0; r < 4; r++) {
                float p = __expf(pvv[j][r] - nm);
                pvv[j][r] = p;
                rs += p;
            }
        rs += __shfl_xor(rs, 16, 64);
        rs += __shfl_xor(rs, 32, 64);
        lrun = lrun * fac + rs;
        mrun = nm;
#pragma unroll
        for (int d = 0; d < 4; d++) oacc[d] *= fac;

        // P^T -> Psl[w][q=li][key] (wave-private, vectorized short4)
#pragma unroll
        for (int j = 0; j < 4; j++) {
            short4 ps;
            ps.x = f2bf(pvv[j][0]); ps.y = f2bf(pvv[j][1]);
            ps.z = f2bf(pvv[j][2]); ps.w = f2bf(pvv[j][3]);
            *(short4*)&Psl[w][li][j * 16 + lg * 4] = ps;
        }

        // O^T += V^T @ P^T
        __builtin_amdgcn_s_setprio(1);
#pragma unroll
        for (int dd = 0; dd < 4; dd++) {
#pragma unroll
            for (int kk = 0; kk < 2; kk++) {
                bf16x8 av = *(const bf16x8*)&Vc[dd * 16 + li][((kk * 4 + lg) ^ xh) * 8];
                bf16x8 pb = *(const bf16x8*)&Psl[w][li][kk * 32 + lg * 8];
                oacc[dd] = __builtin_amdgcn_mfma_f32_16x16x32_bf16(av, pb, oacc[dd], 0, 0, 0);
            }
        }
        __builtin_amdgcn_s_setprio(0);

        wait_vm0_barrier();
        short (*tp)[64];
        tp = Kc; Kc = Kn; Kn = tp;
        tp = Vc; Vc = Vn; Vn = tp;
    }

    // epilogue: O[q][d] = O^T[d][q]/l ; vectorized short4 stores
    if (myq < NTOK) {
        float inv = 1.0f / lrun;
        short* op = aout + ((size_t)b * NTOK + myq) * EMB + h * HD;
#pragma unroll
        for (int dd = 0; dd < 4; dd++) {
            short4 o;
            o.x = f2bf(oacc[dd][0] * inv);
            o.y = f2bf(oacc[dd][1] * inv);
            o.z = f2bf(oacc[dd][2] * inv);
            o.w = f2bf(oacc[dd][3] * inv);
            *(short4*)&op[dd * 16 + lg * 4] = o;
        }
    }
}

// ---------------------------------------------------------------- launch
extern "C" void kernel_launch(void* const* d_in, const int* in_sizes, int n_in,
                              void* d_out, int out_size, void* d_ws, size_t ws_size,
                              hipStream_t stream) {
    (void)in_sizes; (void)n_in; (void)out_size; (void)ws_size;
    const float* x   = (const float*)d_in[0];
    const float* Wq  = (const float*)d_in[1];
    const float* bq  = (const float*)d_in[2];
    const float* Wk  = (const float*)d_in[3];
    const float* bk  = (const float*)d_in[4];
    const float* Wv  = (const float*)d_in[5];
    const float* bv  = (const float*)d_in[6];
    const float* Wp  = (const float*)d_in[7];
    const float* bp  = (const float*)d_in[8];
    const float* rel = (const float*)d_in[9];

    const size_t WN = (size_t)EMB * EMB;                    // 589824
    short* Wb   = (short*)d_ws;                             // [2304][768] bf16
    short* Wpb  = Wb + 3 * WN;                              // [768][768] bf16
    short* qnat = Wpb + WN;                                 // [MROWS][2304] bf16
    short* xb   = qnat + (size_t)MROWS * QKVC;              // [MROWS][768] bf16
    short* aout = xb;                                       // ALIAS: xb dead after gemm0
    short* vtb  = xb + (size_t)MROWS * EMB;                 // [B][H][HD][640] bf16
    short* bexp = vtb + (size_t)BATCH * NHEAD * HD * NPAD;  // [H][640][640] bf16 (q-major)

    const int XN = MROWS * EMB;  // 14180352
    const int MT = (MROWS + 255) / 256;   // 73
    cast_f32_bf16<<<576, 256, 0, stream>>>(Wq, Wb, (int)WN);
    cast_f32_bf16<<<576, 256, 0, stream>>>(Wk, Wb + WN, (int)WN);
    cast_f32_bf16<<<576, 256, 0, stream>>>(Wv, Wb + 2 * WN, (int)WN);
    cast_f32_bf16<<<576, 256, 0, stream>>>(Wp, Wpb, (int)WN);
    cast_f32_bf16<<<13848, 256, 0, stream>>>(x, xb, XN);
    bias_expand<<<NPAD, NPAD, 0, stream>>>(rel, bexp);

    gemm_bt<0><<<9 * MT, 512, 0, stream>>>(xb, Wb, bq, bk, bv, qnat, MROWS);
    transpose_v<<<BATCH * NHEAD * NKT, 256, 0, stream>>>(qnat, vtb);
    attn_kernel<<<BATCH * NHEAD * NQT, 512, 0, stream>>>(qnat, vtb, bexp, aout);
    gemm_bt<1><<<3 * MT, 512, 0, stream>>>(aout, Wpb, bp, bp, bp, d_out, MROWS);
}

// Round 9
// 282.543 us; speedup vs baseline: 1.3870x; 1.0678x over previous
//
#include <hip/hip_runtime.h>
#include <stdint.h>

#define HGT   24
#define WID   24
#define NHEAD 12
#define EMB   768
#define HD    64
#define NGRID 576
#define NTOK  577
#define NPAD  640              // padded token dim (10 tiles of 64)
#define BATCH 32
#define MROWS (BATCH * NTOK)   // 18464
#define NKT   10
#define NQT   5                // 5 q-tiles of 128
#define QKVC  (3 * EMB)        // 2304

typedef __attribute__((ext_vector_type(8))) short bf16x8;
typedef __attribute__((ext_vector_type(4))) float f32x4;

__device__ __forceinline__ short f2bf(float f) {
    union { float f; unsigned u; } c; c.f = f;
    unsigned r = (c.u + 0x7FFFu + ((c.u >> 16) & 1u)) >> 16;
    return (short)(r & 0xFFFFu);
}
__device__ __forceinline__ float b2f(short s) {
    union { unsigned u; float f; } c; c.u = ((unsigned)(unsigned short)s) << 16;
    return c.f;
}

// async global->LDS, 16B per lane; LDS dest = wave-uniform base + lane*16
__device__ __forceinline__ void gload16(void* lds, const void* g) {
    __builtin_amdgcn_global_load_lds(
        (const __attribute__((address_space(1))) void*)g,
        (__attribute__((address_space(3))) void*)lds, 16, 0, 0);
}

__device__ __forceinline__ void wait_vm0_barrier() {
    asm volatile("s_waitcnt vmcnt(0)" ::: "memory");
    __builtin_amdgcn_s_barrier();
}

// bijective XCD-chunk swizzle (m204)
__device__ __forceinline__ int xcd_swizzle(int orig, int nwg) {
    int q = nwg >> 3, r = nwg & 7;
    int xcd = orig & 7, idx = orig >> 3;
    return (xcd < r) ? xcd * (q + 1) + idx : r * (q + 1) + (xcd - r) * q + idx;
}

// ---------------------------------------------------------------- cast f32->bf16
__global__ void cast_f32_bf16(const float* __restrict__ src, short* __restrict__ dst, int n) {
    int i = (blockIdx.x * blockDim.x + threadIdx.x) * 4;
    int stride = gridDim.x * blockDim.x * 4;
    for (int j = i; j < n; j += stride) {
        float4 v = *(const float4*)(src + j);
        short4 o;
        o.x = f2bf(v.x); o.y = f2bf(v.y); o.z = f2bf(v.z); o.w = f2bf(v.w);
        *(short4*)(dst + j) = o;
    }
}

// ---------------------------------------------------------------- bias table bf16 [H][q 640][k 640]
__global__ void bias_expand(const float* __restrict__ rel, short* __restrict__ be) {
    int q = blockIdx.x;     // query 0..639
    int k = threadIdx.x;    // key   0..639
    float v[NHEAD];
    if (k >= NTOK) {
#pragma unroll
        for (int h = 0; h < NHEAD; h++) v[h] = -1e30f;
    } else if (q == 0 || q >= NTOK || k == 0) {
#pragma unroll
        for (int h = 0; h < NHEAD; h++) v[h] = 0.f;
    } else {
        int i = q - 1, j = k - 1;
        int idx = ((i / WID) - (j / WID) + HGT - 1) * (2 * WID - 1)
                + ((i % WID) - (j % WID) + WID - 1);
        const float* rp = rel + (size_t)idx * NHEAD;
#pragma unroll
        for (int h = 0; h < NHEAD; h++) v[h] = rp[h];
    }
#pragma unroll
    for (int h = 0; h < NHEAD; h++)
        be[((size_t)h * NPAD + q) * NPAD + k] = f2bf(v[h]);
}

// ---------------------------------------------------------------- V transpose from qnat: vt[b][h][d][key(640)]
__global__ __launch_bounds__(256) void transpose_v(const short* __restrict__ qnat, short* __restrict__ vt) {
    __shared__ __align__(16) short T[64][72];
    int bi = blockIdx.x;
    int kt = bi % NKT;
    int h  = (bi / NKT) % NHEAD;
    int b  = bi / (NKT * NHEAD);
    int t  = threadIdx.x;

    int r  = t >> 2, cb = (t & 3) * 16;
    int key = kt * 64 + r; if (key >= NTOK) key = NTOK - 1;
    const short* src = qnat + (size_t)(b * NTOK + key) * QKVC + 2 * EMB + h * HD;
    *(int4*)&T[r][cb]     = *(const int4*)(src + cb);
    *(int4*)&T[r][cb + 8] = *(const int4*)(src + cb + 8);
    __syncthreads();

    int d = t >> 2, kb = (t & 3) * 16;
    short tmp[16];
#pragma unroll
    for (int s = 0; s < 16; s++) tmp[s] = T[kb + s][d];
    short* dst = vt + (((size_t)b * NHEAD + h) * HD + d) * NPAD + kt * 64 + kb;
    *(int4*)&dst[0] = *(int4*)&tmp[0];
    *(int4*)&dst[8] = *(int4*)&tmp[8];
}

// ---------------------------------------------------------------- GEMM  C = A @ B^T (+bias)
// 256x256 tile, BK=32, 8 waves (512 thr), 4 LDS buffers, uniform 3-step
// prefetch distance, counted vmcnt(8) (never 0 until tail), ONE barrier/step.
// Transposed accumulation (mfma(B,A)) -> wide C stores.
// MODE 0: NC=2304, bf16 out -> qnat[m][2304]; MODE 1: NC=768, f32 out + b0
template <int MODE>
__global__ __launch_bounds__(512) void gemm_bt(
    const short* __restrict__ A, const short* __restrict__ Bw,
    const float* __restrict__ b0, const float* __restrict__ b1, const float* __restrict__ b2,
    void* __restrict__ Outp, int M)
{
    constexpr int NC  = (MODE == 0) ? QKVC : EMB;
    constexpr int NBX = NC / 256;     // 9 or 3
    constexpr int K   = EMB;          // 768
    constexpr int NST = K / 32;       // 24 K-steps

    __shared__ __align__(16) short Asl[4][256][32];   // 64 KB
    __shared__ __align__(16) short Bsl[4][256][32];   // 64 KB

    const int t    = threadIdx.x;
    const int lane = t & 63;
    const int w    = t >> 6;          // 0..7
    const int wm   = w >> 2;          // 0..1  (M half)
    const int wn   = w & 3;           // 0..3  (N quarter)
    const int lg   = lane >> 4;
    const int li   = lane & 15;

    const int nwg  = NBX * ((MROWS + 255) / 256);     // 9*73 or 3*73
    const int wgid = xcd_swizzle(blockIdx.x, nwg);
    const int tm   = (wgid / NBX) * 256;
    const int tn   = (wgid % NBX) * 256;

    // DMA geometry: one block-wide gload covers 128 rows of 64B; wave w covers
    // 16 rows (w*16 + (l>>2)); lane l writes phys chunk l&3 of its row.
    // Source fetches logical chunk (l&3)^((l>>3)&3)  [store-side swizzle]
    const int drow = lane >> 2;                        // 0..15
    const int lc   = (lane & 3) ^ ((lane >> 3) & 3);   // source logical chunk
    const int xsw  = (li >> 1) & 3;                    // read-side chunk XOR

    const short* agp[2];
    const short* bgp[2];
#pragma unroll
    for (int gi = 0; gi < 2; gi++) {
        int rm = tm + gi * 128 + w * 16 + drow; if (rm >= M) rm = M - 1;
        agp[gi] = A  + (size_t)rm * K + lc * 8;
        bgp[gi] = Bw + (size_t)(tn + gi * 128 + w * 16 + drow) * K + lc * 8;
    }

    f32x4 acc[8][4];
#pragma unroll
    for (int i = 0; i < 8; i++)
#pragma unroll
        for (int j = 0; j < 4; j++) acc[i][j] = (f32x4){0.f, 0.f, 0.f, 0.f};

    // prologue: stage steps 0..2 (4 gloads/wave each)
#pragma unroll
    for (int ss = 0; ss < 3; ss++) {
        gload16(&Asl[ss][0 * 128 + w * 16][0], agp[0] + ss * 32);
        gload16(&Asl[ss][1 * 128 + w * 16][0], agp[1] + ss * 32);
        gload16(&Bsl[ss][0 * 128 + w * 16][0], bgp[0] + ss * 32);
        gload16(&Bsl[ss][1 * 128 + w * 16][0], bgp[1] + ss * 32);
    }

    for (int s = 0; s < NST; s++) {
        // step-s chunks were issued at s-3: wait only until they land
        if (s < NST - 2)       asm volatile("s_waitcnt vmcnt(8)" ::: "memory");
        else if (s == NST - 2) asm volatile("s_waitcnt vmcnt(4)" ::: "memory");
        else                   asm volatile("s_waitcnt vmcnt(0)" ::: "memory");
        __builtin_amdgcn_s_barrier();

        const int cb = s & 3;
        bf16x8 af[8], bfv[4];
#pragma unroll
        for (int mi = 0; mi < 8; mi++)
            af[mi] = *(const bf16x8*)&Asl[cb][wm * 128 + mi * 16 + li][(lg ^ xsw) * 8];
#pragma unroll
        for (int nj = 0; nj < 4; nj++)
            bfv[nj] = *(const bf16x8*)&Bsl[cb][wn * 64 + nj * 16 + li][(lg ^ xsw) * 8];

        // stage step s+3 into the buffer freed at step s-1
        if (s + 3 < NST) {
            const int tb = (s + 3) & 3;
            const int ko = (s + 3) * 32;
            gload16(&Asl[tb][0 * 128 + w * 16][0], agp[0] + ko);
            gload16(&Asl[tb][1 * 128 + w * 16][0], agp[1] + ko);
            gload16(&Bsl[tb][0 * 128 + w * 16][0], bgp[0] + ko);
            gload16(&Bsl[tb][1 * 128 + w * 16][0], bgp[1] + ko);
        }

        __builtin_amdgcn_s_setprio(1);
#pragma unroll
        for (int mi = 0; mi < 8; mi++)
#pragma unroll
            for (int nj = 0; nj < 4; nj++)
                acc[mi][nj] = __builtin_amdgcn_mfma_f32_16x16x32_bf16(
                    bfv[nj], af[mi], acc[mi][nj], 0, 0, 0);   // transposed: C^T frags
        __builtin_amdgcn_s_setprio(0);
    }

    // epilogue: lane holds C[row = wm*128+mi*16+li][cols = ccb..ccb+3]
#pragma unroll
    for (int nj = 0; nj < 4; nj++) {
        const int ccb = tn + wn * 64 + nj * 16 + lg * 4;
        float4 bias4;
        if constexpr (MODE == 0) {
            int which = (ccb >= 2 * EMB) ? 2 : ((ccb >= EMB) ? 1 : 0);
            const float* bb = (which == 0) ? b0 : ((which == 1) ? b1 : b2);
            bias4 = *(const float4*)&bb[ccb - which * EMB];
        } else {
            bias4 = *(const float4*)&b0[ccb];
        }
#pragma unroll
        for (int mi = 0; mi < 8; mi++) {
            int m = tm + wm * 128 + mi * 16 + li;
            if (m >= M) continue;
            if constexpr (MODE == 0) {
                short4 o;
                o.x = f2bf(acc[mi][nj][0] + bias4.x);
                o.y = f2bf(acc[mi][nj][1] + bias4.y);
                o.z = f2bf(acc[mi][nj][2] + bias4.z);
                o.w = f2bf(acc[mi][nj][3] + bias4.w);
                *(short4*)&((short*)Outp)[(size_t)m * NC + ccb] = o;
            } else {
                float4 o;
                o.x = acc[mi][nj][0] + bias4.x;
                o.y = acc[mi][nj][1] + bias4.y;
                o.z = acc[mi][nj][2] + bias4.z;
                o.w = acc[mi][nj][3] + bias4.w;
                *(float4*)&((float*)Outp)[(size_t)m * NC + ccb] = o;
            }
        }
    }
}

// ---------------------------------------------------------------- flash attention (swapped QK^T)
// 512 threads (8 waves x 16 queries = 128 q per block); h-major block order + XCD chunk swizzle
__global__ __launch_bounds__(512) void attn_kernel(
    const short* __restrict__ qnat, const short* __restrict__ vt,
    const short* __restrict__ biasx, short* __restrict__ aout)
{
    __shared__ __align__(16) short Ksl[2][64][64];
    __shared__ __align__(16) short Vsl[2][64][64];   // [d][key_local]
    __shared__ __align__(16) short Psl[8][16][72];   // [wave][q(li)][key]

    // chunked swizzle (1920 % 8 == 0) + h-major decomposition
    const int wg = (blockIdx.x & 7) * (BATCH * NHEAD * NQT / 8) + (blockIdx.x >> 3);
    const int qt = wg % NQT;
    const int rest = wg / NQT;        // 0..383
    const int b  = rest & 31;
    const int h  = rest >> 5;

    const int t    = threadIdx.x;
    const int lane = t & 63;
    const int w    = t >> 6;          // 0..7
    const int lg   = lane >> 4;
    const int li   = lane & 15;
    const int xh   = li & 7;
    const int qbase = qt * 128;
    const int myq  = qbase + w * 16 + li;   // this lane's query column

    const short* qp  = qnat + (size_t)b * NTOK * QKVC + h * HD;          // + n*QKVC
    const short* kp  = qp + EMB;
    const short* vtp = vt + ((size_t)b * NHEAD + h) * (size_t)HD * NPAD;
    const short* browq = biasx + ((size_t)h * NPAD + myq) * NPAD;        // [k] bf16

    bf16x8 qf[2];   // B-fragment: Q[myq][k]
    {
        int qrow = myq < NTOK ? myq : NTOK - 1;
        qf[0] = *(const bf16x8*)(qp + (size_t)qrow * QKVC + lg * 8);
        qf[1] = *(const bf16x8*)(qp + (size_t)qrow * QKVC + 32 + lg * 8);
    }

    float mrun = -1e30f, lrun = 0.f;
    f32x4 oacc[4];
#pragma unroll
    for (int d = 0; d < 4; d++) oacc[d] = (f32x4){0.f, 0.f, 0.f, 0.f};

    const int srow = w * 8 + (lane >> 3);
    const int cofs = ((lane & 7) ^ (lane >> 3)) * 8;

    {
        int key = srow; if (key >= NTOK) key = NTOK - 1;
        gload16(&Ksl[0][w * 8][0], kp + (size_t)key * QKVC + cofs);
        gload16(&Vsl[0][w * 8][0], vtp + (size_t)srow * NPAD + cofs);
    }
    wait_vm0_barrier();

    short (*Kc)[64] = Ksl[0], (*Kn)[64] = Ksl[1];
    short (*Vc)[64] = Vsl[0], (*Vn)[64] = Vsl[1];

    for (int kt = 0; kt < NKT; kt++) {
        if (kt + 1 < NKT) {
            int key = (kt + 1) * 64 + srow; if (key >= NTOK) key = NTOK - 1;
            gload16(&Kn[w * 8][0], kp + (size_t)key * QKVC + cofs);
            gload16(&Vn[w * 8][0], vtp + (size_t)srow * NPAD + (kt + 1) * 64 + cofs);
        }

        // S^T = K @ Q^T + bias^T
        float pvv[4][4];
        __builtin_amdgcn_s_setprio(1);
#pragma unroll
        for (int j = 0; j < 4; j++) {
            short4 bs = *(const short4*)&browq[kt * 64 + j * 16 + lg * 4];
            bf16x8 ak0 = *(const bf16x8*)&Kc[j * 16 + li][(lg ^ xh) * 8];
            bf16x8 ak1 = *(const bf16x8*)&Kc[j * 16 + li][((4 + lg) ^ xh) * 8];
            f32x4 s = (f32x4){0.f, 0.f, 0.f, 0.f};
            s = __builtin_amdgcn_mfma_f32_16x16x32_bf16(ak0, qf[0], s, 0, 0, 0);
            s = __builtin_amdgcn_mfma_f32_16x16x32_bf16(ak1, qf[1], s, 0, 0, 0);
            pvv[j][0] = fmaf(s[0], 0.125f, b2f(bs.x));
            pvv[j][1] = fmaf(s[1], 0.125f, b2f(bs.y));
            pvv[j][2] = fmaf(s[2], 0.125f, b2f(bs.z));
            pvv[j][3] = fmaf(s[3], 0.125f, b2f(bs.w));
        }
        __builtin_amdgcn_s_setprio(0);

        // online softmax: one query per lane; reduce across the 4 lg-lanes
        float mt = pvv[0][0];
#pragma unroll
        for (int j = 0; j < 4; j++)
#pragma unroll
            for (int r = 0; r < 4; r++) mt = fmaxf(mt, pvv[j][r]);
        mt = fmaxf(mt, __shfl_xor(mt, 16, 64));
        mt = fmaxf(mt, __shfl_xor(mt, 32, 64));
        float nm  = fmaxf(mrun, mt);
        float fac = __expf(mrun - nm);
        float rs  = 0.f;
#pragma unroll
        for (int j = 0; j < 4; j++)
#pragma unroll
            for (int r = 0; r < 4; r++) {
                float p = __expf(pvv[j][r] - nm);
                pvv[j][r] = p;
                rs += p;
            }
        rs += __shfl_xor(rs, 16, 64);
        rs += __shfl_xor(rs, 32, 64);
        lrun = lrun * fac + rs;
        mrun = nm;
#pragma unroll
        for (int d = 0; d < 4; d++) oacc[d] *= fac;

        // P^T -> Psl[w][q=li][key] (wave-private, vectorized short4)
#pragma unroll
        for (int j = 0; j < 4; j++) {
            short4 ps;
            ps.x = f2bf(pvv[j][0]); ps.y = f2bf(pvv[j][1]);
            ps.z = f2bf(pvv[j][2]); ps.w = f2bf(pvv[j][3]);
            *(short4*)&Psl[w][li][j * 16 + lg * 4] = ps;
        }

        // O^T += V^T @ P^T
        __builtin_amdgcn_s_setprio(1);
#pragma unroll
        for (int dd = 0; dd < 4; dd++) {
#pragma unroll
            for (int kk = 0; kk < 2; kk++) {
                bf16x8 av = *(const bf16x8*)&Vc[dd * 16 + li][((kk * 4 + lg) ^ xh) * 8];
                bf16x8 pb = *(const bf16x8*)&Psl[w][li][kk * 32 + lg * 8];
                oacc[dd] = __builtin_amdgcn_mfma_f32_16x16x32_bf16(av, pb, oacc[dd], 0, 0, 0);
            }
        }
        __builtin_amdgcn_s_setprio(0);

        wait_vm0_barrier();
        short (*tp)[64];
        tp = Kc; Kc = Kn; Kn = tp;
        tp = Vc; Vc = Vn; Vn = tp;
    }

    // epilogue: O[q][d] = O^T[d][q]/l ; vectorized short4 stores
    if (myq < NTOK) {
        float inv = 1.0f / lrun;
        short* op = aout + ((size_t)b * NTOK + myq) * EMB + h * HD;
#pragma unroll
        for (int dd = 0; dd < 4; dd++) {
            short4 o;
            o.x = f2bf(oacc[dd][0] * inv);
            o.y = f2bf(oacc[dd][1] * inv);
            o.z = f2bf(oacc[dd][2] * inv);
            o.w = f2bf(oacc[dd][3] * inv);
            *(short4*)&op[dd * 16 + lg * 4] = o;
        }
    }
}

// ---------------------------------------------------------------- launch
extern "C" void kernel_launch(void* const* d_in, const int* in_sizes, int n_in,
                              void* d_out, int out_size, void* d_ws, size_t ws_size,
                              hipStream_t stream) {
    (void)in_sizes; (void)n_in; (void)out_size; (void)ws_size;
    const float* x   = (const float*)d_in[0];
    const float* Wq  = (const float*)d_in[1];
    const float* bq  = (const float*)d_in[2];
    const float* Wk  = (const float*)d_in[3];
    const float* bk  = (const float*)d_in[4];
    const float* Wv  = (const float*)d_in[5];
    const float* bv  = (const float*)d_in[6];
    const float* Wp  = (const float*)d_in[7];
    const float* bp  = (const float*)d_in[8];
    const float* rel = (const float*)d_in[9];

    const size_t WN = (size_t)EMB * EMB;                    // 589824
    short* Wb   = (short*)d_ws;                             // [2304][768] bf16
    short* Wpb  = Wb + 3 * WN;                              // [768][768] bf16
    short* qnat = Wpb + WN;                                 // [MROWS][2304] bf16
    short* xb   = qnat + (size_t)MROWS * QKVC;              // [MROWS][768] bf16
    short* aout = xb;                                       // ALIAS: xb dead after gemm0
    short* vtb  = xb + (size_t)MROWS * EMB;                 // [B][H][HD][640] bf16
    short* bexp = vtb + (size_t)BATCH * NHEAD * HD * NPAD;  // [H][640][640] bf16 (q-major)

    const int XN = MROWS * EMB;  // 14180352
    const int MT = (MROWS + 255) / 256;   // 73
    cast_f32_bf16<<<576, 256, 0, stream>>>(Wq, Wb, (int)WN);
    cast_f32_bf16<<<576, 256, 0, stream>>>(Wk, Wb + WN, (int)WN);
    cast_f32_bf16<<<576, 256, 0, stream>>>(Wv, Wb + 2 * WN, (int)WN);
    cast_f32_bf16<<<576, 256, 0, stream>>>(Wp, Wpb, (int)WN);
    cast_f32_bf16<<<13848, 256, 0, stream>>>(x, xb, XN);
    bias_expand<<<NPAD, NPAD, 0, stream>>>(rel, bexp);

    gemm_bt<0><<<9 * MT, 512, 0, stream>>>(xb, Wb, bq, bk, bv, qnat, MROWS);
    transpose_v<<<BATCH * NHEAD * NKT, 256, 0, stream>>>(qnat, vtb);
    attn_kernel<<<BATCH * NHEAD * NQT, 512, 0, stream>>>(qnat, vtb, bexp, aout);
    gemm_bt<1><<<3 * MT, 512, 0, stream>>>(aout, Wpb, bp, bp, bp, d_out, MROWS);
}